// Round 15
// baseline (179.593 us; speedup 1.0000x reference)
//
#include <hip/hip_runtime.h>

typedef unsigned short u16;
typedef unsigned long long u64;
typedef __attribute__((ext_vector_type(4))) float f32x4;
typedef __attribute__((ext_vector_type(8))) short s16x8;
typedef __attribute__((ext_vector_type(4))) short s16x4;
typedef __attribute__((ext_vector_type(4))) unsigned int u32x4;

#define LDS_LOAD16(gp, lp) __builtin_amdgcn_global_load_lds( \
    (__attribute__((address_space(1))) void*)(gp), \
    (__attribute__((address_space(3))) void*)(lp), 16, 0, 0)

#define MFMA16 __builtin_amdgcn_mfma_f32_16x16x32_bf16

constexpr float L2E = 1.44269504088896340736f;

__device__ __forceinline__ u16 f2bf(float x) {
  unsigned u = __float_as_uint(x);
  u += 0x7FFF + ((u >> 16) & 1);   // RNE
  return (u16)(u >> 16);
}

__device__ __forceinline__ unsigned cvtpk_bf16(float lo, float hi) {
  unsigned r;
  asm("v_cvt_pk_bf16_f32 %0, %1, %2" : "=v"(r) : "v"(lo), "v"(hi));
  return r;
}

// ---------------------------------------------------------------- convert
struct ConvArgs {
  const float* src[7];
  u16* dst[7];
  int n4[7];
  float scale[7];
};

__global__ __launch_bounds__(256) void convert_many(ConvArgs a) {
  const int arr = blockIdx.y;
  const f32x4* src = (const f32x4*)a.src[arr];
  u16* dst = a.dst[arr];
  const int n4 = a.n4[arr];
  const float sc = a.scale[arr];
  const int stride = gridDim.x * blockDim.x;
  for (int i = blockIdx.x * blockDim.x + threadIdx.x; i < n4; i += stride) {
    f32x4 v = src[i];
    s16x4 o;
#pragma unroll
    for (int j = 0; j < 4; ++j) o[j] = (short)f2bf(v[j] * sc);
    *(s16x4*)(dst + (size_t)i * 4) = o;
  }
}

// ---------------------------------------------------------------- mask -> bits (standalone, fallback path)
__global__ __launch_bounds__(256) void mask_to_bits(const unsigned int* __restrict__ m32,
                                                    u64* __restrict__ bits,
                                                    int n) {
  const int lane = threadIdx.x & 63;
  unsigned probe = m32[lane];
  bool bytemode = __any(probe > 1u);
  const int stride = gridDim.x * blockDim.x;
  for (int i = blockIdx.x * blockDim.x + threadIdx.x; i < n; i += stride) {
    bool v;
    if (bytemode) v = ((const unsigned char*)m32)[i] != 0;
    else          v = m32[i] != 0;
    u64 b = __ballot(v);
    if (lane == 0) bits[i >> 6] = b;
  }
}

// ---------------------------------------------------------------- QKV GEMM (bf16, T4) + fused mask pack
// z<3: C = A*B^T (+bias*bscale), 3-buffer LDS, counted vmcnt, raw barriers.
// z==3: grid-strided mask->bits pack (consumed only by the NEXT kernel).
struct QkvArgsB {
  const u16* A[3];
  const u16* B[3];
  const float* bias[3];
  float bscale[3];
  u16* C[3];
  const unsigned* mask;
  u64* bits;
  int nmask;
};

__global__ __launch_bounds__(256) void gemm_qkv_bf(QkvArgsB a) {
  const int z = blockIdx.z;
  if (z == 3) {
    const int lane = threadIdx.x & 63;
    unsigned probe = a.mask[lane];
    bool bytemode = __any(probe > 1u);
    const int nb = gridDim.x * gridDim.y;
    const int bid = blockIdx.y * gridDim.x + blockIdx.x;
    const int stride = nb * blockDim.x;
    for (int i = bid * blockDim.x + threadIdx.x; i < a.nmask; i += stride) {
      bool v;
      if (bytemode) v = ((const unsigned char*)a.mask)[i] != 0;
      else          v = a.mask[i] != 0;
      u64 b = __ballot(v);
      if (lane == 0) a.bits[i >> 6] = b;
    }
    return;
  }
  const u16* __restrict__ A = a.A[z];
  const u16* __restrict__ B = a.B[z];
  const float* __restrict__ bias = a.bias[z];
  const float bscale = a.bscale[z];
  u16* __restrict__ C = a.C[z];

  __shared__ u16 As[3][4096];
  __shared__ u16 Bs[3][4096];
  const int tid = threadIdx.x;
  const int lane = tid & 63;
  const int wave = tid >> 6;
  const int g = lane >> 4, c = lane & 15;
  const int g4 = g * 4;
  const int bx = blockIdx.x;
  const int row0 = (((bx & 7) << 2) | (bx >> 3)) * 128;   // XCD-chunked rows
  const int col0 = blockIdx.y * 128;
  const int wr = (wave >> 1) * 64, wc = (wave & 1) * 64;

  f32x4 acc[4][4] = {};

#define STAGE_QKV(p_, k0_) { _Pragma("unroll") \
    for (int i = 0; i < 2; ++i) { \
      int e = (i * 256 + tid) * 8; \
      LDS_LOAD16(A + (size_t)(row0 + (e >> 5)) * 1024 + (k0_) + (e & 31), As[p_] + e); \
      LDS_LOAD16(B + (size_t)(col0 + (e >> 5)) * 1024 + (k0_) + (e & 31), Bs[p_] + e); } }

  STAGE_QKV(0, 0);
  STAGE_QKV(1, 32);

  for (int s = 0; s < 32; ++s) {
    const int p = s % 3;
    if (s == 31) asm volatile("s_waitcnt vmcnt(0)" ::: "memory");
    else         asm volatile("s_waitcnt vmcnt(4)" ::: "memory");
    __builtin_amdgcn_s_barrier();
    __builtin_amdgcn_sched_barrier(0);
    if (s + 2 < 32) {
      const int np = (s + 2) % 3;
      STAGE_QKV(np, (s + 2) * 32);
    }
    s16x8 af[4], bf[4];
#pragma unroll
    for (int m = 0; m < 4; ++m) af[m] = *(const s16x8*)(As[p] + (wr + m * 16 + c) * 32 + g * 8);
#pragma unroll
    for (int n = 0; n < 4; ++n) bf[n] = *(const s16x8*)(Bs[p] + (wc + n * 16 + c) * 32 + g * 8);
#pragma unroll
    for (int m = 0; m < 4; ++m)
#pragma unroll
      for (int n = 0; n < 4; ++n)
        acc[m][n] = MFMA16(bf[n], af[m], acc[m][n], 0, 0, 0);   // swapped
  }

  f32x4 bv[4];
#pragma unroll
  for (int n = 0; n < 4; ++n) {
    bv[n] = *(const f32x4*)(bias + col0 + wc + n * 16 + g4);
#pragma unroll
    for (int r = 0; r < 4; ++r) bv[n][r] *= bscale;
  }
#pragma unroll
  for (int m = 0; m < 4; ++m)
#pragma unroll
    for (int n = 0; n < 4; ++n) {
      s16x4 o;
#pragma unroll
      for (int r = 0; r < 4; ++r) o[r] = (short)f2bf(acc[m][n][r] + bv[n][r]);
      *(s16x4*)(C + (size_t)(row0 + wr + m * 16 + c) * 1024 + col0 + wc + n * 16 + g4) = o;
    }
}

// ---------------------------------------------------------------- QKV GEMM (fp32 A, fallback)
struct QkvArgsF {
  const float* A[3];
  const u16* B[3];
  const float* bias[3];
  float bscale[3];
  u16* C[3];
};

__global__ __launch_bounds__(256) void gemm_qkv_f32(QkvArgsF a) {
  const int z = blockIdx.z;
  const float* __restrict__ A = a.A[z];
  const u16* __restrict__ B = a.B[z];
  const float* __restrict__ bias = a.bias[z];
  const float bscale = a.bscale[z];
  u16* __restrict__ C = a.C[z];

  __shared__ u16 As[2][4096];
  __shared__ u16 Bs[2][4096];
  const int tid = threadIdx.x;
  const int lane = tid & 63;
  const int wave = tid >> 6;
  const int g = lane >> 4, c = lane & 15;
  const int g4 = g * 4;
  const int row0 = blockIdx.x * 128;
  const int col0 = blockIdx.y * 128;
  const int wr = (wave >> 1) * 64, wc = (wave & 1) * 64;
  const int ra = tid >> 2;
  const int cca = (tid & 3) * 8;

  f32x4 acc[4][4] = {};
  f32x4 ar[2][2];
#pragma unroll
  for (int i = 0; i < 2; ++i) {
    ar[i][0] = *(const f32x4*)(A + (size_t)(row0 + i * 64 + ra) * 1024 + cca);
    ar[i][1] = *(const f32x4*)(A + (size_t)(row0 + i * 64 + ra) * 1024 + cca + 4);
  }

  for (int s = 0; s < 32; ++s) {
    const int p = s & 1;
    const int k0 = s * 32;
#pragma unroll
    for (int i = 0; i < 2; ++i) {
      unsigned w0 = cvtpk_bf16(ar[i][0][0], ar[i][0][1]);
      unsigned w1 = cvtpk_bf16(ar[i][0][2], ar[i][0][3]);
      unsigned w2 = cvtpk_bf16(ar[i][1][0], ar[i][1][1]);
      unsigned w3 = cvtpk_bf16(ar[i][1][2], ar[i][1][3]);
      union { u32x4 u; s16x8 v; } w;
      w.u = (u32x4){w0, w1, w2, w3};
      *(s16x8*)(As[p] + (i * 256 + tid) * 8) = w.v;
    }
    if (s < 31) {
#pragma unroll
      for (int i = 0; i < 2; ++i) {
        ar[i][0] = *(const f32x4*)(A + (size_t)(row0 + i * 64 + ra) * 1024 + k0 + 32 + cca);
        ar[i][1] = *(const f32x4*)(A + (size_t)(row0 + i * 64 + ra) * 1024 + k0 + 32 + cca + 4);
      }
    }
#pragma unroll
    for (int i = 0; i < 2; ++i) {
      int e = (i * 256 + tid) * 8;
      LDS_LOAD16(B + (size_t)(col0 + (e >> 5)) * 1024 + k0 + (e & 31), Bs[p] + e);
    }
    __syncthreads();

    s16x8 af[4], bf[4];
#pragma unroll
    for (int m = 0; m < 4; ++m) af[m] = *(const s16x8*)(As[p] + (wr + m * 16 + c) * 32 + g * 8);
#pragma unroll
    for (int n = 0; n < 4; ++n) bf[n] = *(const s16x8*)(Bs[p] + (wc + n * 16 + c) * 32 + g * 8);
#pragma unroll
    for (int m = 0; m < 4; ++m)
#pragma unroll
      for (int n = 0; n < 4; ++n)
        acc[m][n] = MFMA16(bf[n], af[m], acc[m][n], 0, 0, 0);
  }

  f32x4 bv[4];
#pragma unroll
  for (int n = 0; n < 4; ++n) {
    bv[n] = *(const f32x4*)(bias + col0 + wc + n * 16 + g4);
#pragma unroll
    for (int r = 0; r < 4; ++r) bv[n][r] *= bscale;
  }
#pragma unroll
  for (int m = 0; m < 4; ++m)
#pragma unroll
    for (int n = 0; n < 4; ++n) {
      s16x4 o;
#pragma unroll
      for (int r = 0; r < 4; ++r) o[r] = (short)f2bf(acc[m][n][r] + bv[n][r]);
      *(s16x4*)(C + (size_t)(row0 + wr + m * 16 + c) * 1024 + col0 + wc + n * 16 + g4) = o;
    }
}

// ---------------------------------------------------------------- out GEMM (T4 pipeline)
__global__ __launch_bounds__(256) void gemm_out(const u16* __restrict__ A,
                                                const u16* __restrict__ B,
                                                const float* __restrict__ bias,
                                                const float* __restrict__ resid,
                                                float* __restrict__ C) {
  __shared__ u16 As[3][2048];
  __shared__ u16 Bs[3][4096];
  const int tid = threadIdx.x;
  const int lane = tid & 63;
  const int wave = tid >> 6;
  const int g = lane >> 4, c = lane & 15;
  const int g4 = g * 4;
  const int bx = blockIdx.x;
  const int row0 = (((bx & 7) << 3) | (bx >> 3)) * 64;    // XCD-chunked rows
  const int col0 = blockIdx.y * 128;
  const int wr = (wave >> 1) * 32, wc = (wave & 1) * 64;

  f32x4 acc[2][4] = {};

#define STAGE_OUT(p_, k0_) { \
    LDS_LOAD16(A + (size_t)(row0 + (tid >> 2)) * 1024 + (k0_) + (tid & 3) * 8, As[p_] + tid * 8); \
    _Pragma("unroll") \
    for (int i = 0; i < 2; ++i) { \
      int e = (i * 256 + tid) * 8; \
      LDS_LOAD16(B + (size_t)(col0 + (e >> 5)) * 1024 + (k0_) + (e & 31), Bs[p_] + e); } }

  STAGE_OUT(0, 0);
  STAGE_OUT(1, 32);

  for (int s = 0; s < 32; ++s) {
    const int p = s % 3;
    if (s == 31) asm volatile("s_waitcnt vmcnt(0)" ::: "memory");
    else         asm volatile("s_waitcnt vmcnt(3)" ::: "memory");
    __builtin_amdgcn_s_barrier();
    __builtin_amdgcn_sched_barrier(0);
    if (s + 2 < 32) {
      const int np = (s + 2) % 3;
      STAGE_OUT(np, (s + 2) * 32);
    }
    s16x8 af[2], bf[4];
#pragma unroll
    for (int m = 0; m < 2; ++m) af[m] = *(const s16x8*)(As[p] + (wr + m * 16 + c) * 32 + g * 8);
#pragma unroll
    for (int n = 0; n < 4; ++n) bf[n] = *(const s16x8*)(Bs[p] + (wc + n * 16 + c) * 32 + g * 8);
#pragma unroll
    for (int m = 0; m < 2; ++m)
#pragma unroll
      for (int n = 0; n < 4; ++n)
        acc[m][n] = MFMA16(bf[n], af[m], acc[m][n], 0, 0, 0);
  }

  f32x4 bv[4];
#pragma unroll
  for (int n = 0; n < 4; ++n) bv[n] = *(const f32x4*)(bias + col0 + wc + n * 16 + g4);
#pragma unroll
  for (int m = 0; m < 2; ++m)
#pragma unroll
    for (int n = 0; n < 4; ++n) {
      size_t off = (size_t)(row0 + wr + m * 16 + c) * 1024 + col0 + wc + n * 16 + g4;
      f32x4 rv = *(const f32x4*)(resid + off);
      f32x4 o;
#pragma unroll
      for (int r = 0; r < 4; ++r) o[r] = acc[m][n][r] + bv[n][r] + rv[r];
      *(f32x4*)(C + off) = o;
    }
}

// ---------------------------------------------------------------- attention (R10 proven: 69 us)
// 128 q-rows/block, 2 q-subtiles/wave, grid 512 (2 blocks/CU). sigma-permuted
// V layout (8xb128 reads land in zero-shuffle pa k-order), v_perm staging
// pack, ones-MFMA denominator, literal-p x2 unroll, 1 barrier/iter.
constexpr float NEGV = -10000000.0f;

__global__ __launch_bounds__(256) void attn_kernel(const u16* __restrict__ Qh,
                                                   const u16* __restrict__ Kh,
                                                   const u16* __restrict__ Vh,
                                                   const u64* __restrict__ mbits,
                                                   const float* __restrict__ head_mask,
                                                   u16* __restrict__ ctx) {
  __shared__ u16 Ks[2][4096];      // d-chunked: [chunk(d/8)][key(64)][d%8]
  __shared__ u16 Vt[2][64 * 72];   // [d][sigma(key) ^ 8*(d>>3)], stride 72

  const int tid = threadIdx.x;
  const int lane = tid & 63;
  const int wave = tid >> 6;
  const int g = lane >> 4, c = lane & 15;
  const int g4 = g * 4;
  const int wid = (blockIdx.x & 7) * 64 + (blockIdx.x >> 3);
  const int qt = wid & 15;
  const int bh = wid >> 4;
  const int b = bh >> 4;
  const int h = bh & 15;
  const size_t rowbase = (size_t)b * 2048;
  const int D = 1024;

  s16x8 qf[2][2];
#pragma unroll
  for (int s = 0; s < 2; ++s) {
    const int qrow = qt * 128 + s * 64 + wave * 16 + c;
#pragma unroll
    for (int ks = 0; ks < 2; ++ks)
      qf[s][ks] = *(const s16x8*)(Qh + (rowbase + qrow) * D + h * 64 + ks * 32 + g * 8);
  }

  f32x4 accO[2][4] = {};
  f32x4 accSum[2] = {};            // ones-MFMA denominator; col q=c

  union { u32x4 u; s16x8 v; } onesu;
  onesu.u = (u32x4){0x3F803F80u, 0x3F803F80u, 0x3F803F80u, 0x3F803F80u};
  const s16x8 onesA = onesu.v;

  const u64* mrow0 = mbits + (rowbase + qt * 128 + 0 * 64 + wave * 16 + c) * 32;
  const u64* mrow1 = mbits + (rowbase + qt * 128 + 1 * 64 + wave * 16 + c) * 32;

  const int kkK = tid & 63;
  const int aV = tid >> 3;
  const int sV = tid & 7;
  const int dcV = sV * 8;
  // sigma(k): k=32K+16H+4G+J -> slot 32K+8G+4H+J  (pairs k=2a,2a+1 stay adjacent)
  const int k2 = 2 * aV;
  const int slotV = (k2 & 32) | (((k2 >> 2) & 3) << 3) | (((k2 >> 4) & 1) << 2) | (k2 & 3);
  const int colV = slotV ^ (8 * sV);

  const u16* Kbase = Kh + rowbase * D + h * 64;
  const u16* Vbase = Vh + rowbase * D + h * 64;

  s16x8 kreg[2], vreg[2];
#define LOADKV(kb_) { \
    kreg[0] = *(const s16x8*)(Kbase + (size_t)((kb_) + kkK) * D + wave * 8); \
    kreg[1] = *(const s16x8*)(Kbase + (size_t)((kb_) + kkK) * D + (4 + wave) * 8); \
    vreg[0] = *(const s16x8*)(Vbase + (size_t)((kb_) + k2) * D + dcV); \
    vreg[1] = *(const s16x8*)(Vbase + (size_t)((kb_) + k2 + 1) * D + dcV); }
#define WRITEKV(p_) { \
    *(s16x8*)(Ks[p_] + tid * 8) = kreg[0]; \
    *(s16x8*)(Ks[p_] + 2048 + tid * 8) = kreg[1]; \
    const unsigned* v0w = (const unsigned*)&vreg[0]; \
    const unsigned* v1w = (const unsigned*)&vreg[1]; \
    _Pragma("unroll") \
    for (int j = 0; j < 8; ++j) { \
      unsigned pk = __builtin_amdgcn_perm(v1w[j >> 1], v0w[j >> 1], \
                                          (j & 1) ? 0x07060302u : 0x05040100u); \
      *(unsigned*)(Vt[p_] + (dcV + j) * 72 + colV) = pk; } }

  LOADKV(0);
  WRITEKV(0);
  LOADKV(64);
  __syncthreads();

#define ATTN_ITER(p_, it_) { \
    const int it = (it_); \
    if (it < 31) WRITEKV(p_ ^ 1); \
    if (it < 30) LOADKV((it + 2) * 64); \
    f32x4 accS[2][4]; \
    _Pragma("unroll") \
    for (int t = 0; t < 4; ++t) { \
      s16x8 kf0 = *(const s16x8*)(Ks[p_] + ((0 + g) * 64 + t * 16 + c) * 8); \
      s16x8 kf1 = *(const s16x8*)(Ks[p_] + ((4 + g) * 64 + t * 16 + c) * 8); \
      f32x4 z0 = {0.f, 0.f, 0.f, 0.f}; \
      z0 = MFMA16(kf0, qf[0][0], z0, 0, 0, 0); \
      accS[0][t] = MFMA16(kf1, qf[0][1], z0, 0, 0, 0); \
      f32x4 z1 = {0.f, 0.f, 0.f, 0.f}; \
      z1 = MFMA16(kf0, qf[1][0], z1, 0, 0, 0); \
      accS[1][t] = MFMA16(kf1, qf[1][1], z1, 0, 0, 0); \
    } \
    s16x8 vbr[4][2]; \
    _Pragma("unroll") \
    for (int d0 = 0; d0 < 4; ++d0) { \
      const int dd = d0 * 16 + c; \
      const int sw8 = (d0 * 2 + (c >> 3)) * 8; \
      _Pragma("unroll") \
      for (int ks = 0; ks < 2; ++ks) \
        vbr[d0][ks] = *(const s16x8*)(Vt[p_] + dd * 72 + ((ks * 32 + g * 8) ^ sw8)); \
    } \
    s16x8 pa[2][2]; \
    _Pragma("unroll") \
    for (int s = 0; s < 2; ++s) { \
      u64 mw = (s == 0 ? mrow0 : mrow1)[it]; \
      u64 sh = mw >> g4; \
      unsigned mlo = (unsigned)sh, mhi = (unsigned)(sh >> 32); \
      unsigned pk0[4], pk1[4]; \
      _Pragma("unroll") \
      for (int t = 0; t < 4; ++t) { \
        unsigned msrc = (t < 2) ? mlo : mhi; \
        _Pragma("unroll") \
        for (int r = 0; r < 4; ++r) { \
          float sv = accS[s][t][r]; \
          if ((msrc >> ((t & 1) * 16 + r)) & 1) sv = NEGV; \
          float pv; \
          asm("v_exp_f32 %0, %1" : "=v"(pv) : "v"(sv)); \
          accS[s][t][r] = pv; \
        } \
        pk0[t] = cvtpk_bf16(accS[s][t][0], accS[s][t][1]); \
        pk1[t] = cvtpk_bf16(accS[s][t][2], accS[s][t][3]); \
      } \
      _Pragma("unroll") \
      for (int ks = 0; ks < 2; ++ks) { \
        union { u32x4 u; s16x8 v; } w; \
        w.u = (u32x4){pk0[2 * ks], pk1[2 * ks], pk0[2 * ks + 1], pk1[2 * ks + 1]}; \
        pa[s][ks] = w.v; \
      } \
    } \
    _Pragma("unroll") \
    for (int d0 = 0; d0 < 4; ++d0) \
      _Pragma("unroll") \
      for (int ks = 0; ks < 2; ++ks) { \
        accO[0][d0] = MFMA16(vbr[d0][ks], pa[0][ks], accO[0][d0], 0, 0, 0); \
        accO[1][d0] = MFMA16(vbr[d0][ks], pa[1][ks], accO[1][d0], 0, 0, 0); \
      } \
    _Pragma("unroll") \
    for (int ks = 0; ks < 2; ++ks) { \
      accSum[0] = MFMA16(onesA, pa[0][ks], accSum[0], 0, 0, 0); \
      accSum[1] = MFMA16(onesA, pa[1][ks], accSum[1], 0, 0, 0); \
    } \
    __syncthreads(); }

  for (int it2 = 0; it2 < 16; ++it2) {
    ATTN_ITER(0, 2 * it2);
    ATTN_ITER(1, 2 * it2 + 1);
  }

  const float hm = head_mask[0];
#pragma unroll
  for (int s = 0; s < 2; ++s) {
    float inv = hm / accSum[s][0];
    const int qrow = qt * 128 + s * 64 + wave * 16 + c;
#pragma unroll
    for (int d0 = 0; d0 < 4; ++d0) {
      s16x4 o;
#pragma unroll
      for (int r = 0; r < 4; ++r) o[r] = (short)f2bf(accO[s][d0][r] * inv);
      *(s16x4*)(ctx + (rowbase + qrow) * D + h * 64 + d0 * 16 + g4) = o;
    }
  }
}

// ---------------------------------------------------------------- launch
extern "C" void kernel_launch(void* const* d_in, const int* in_sizes, int n_in,
                              void* d_out, int out_size, void* d_ws, size_t ws_size,
                              hipStream_t stream) {
  const float* q  = (const float*)d_in[0];
  const float* k  = (const float*)d_in[1];
  const float* v  = (const float*)d_in[2];
  const void*  am = d_in[3];
  const float* hm = (const float*)d_in[4];
  const float* Wq = (const float*)d_in[5];
  const float* bq = (const float*)d_in[6];
  const float* Wk = (const float*)d_in[7];
  const float* bk = (const float*)d_in[8];
  const float* Wv = (const float*)d_in[9];
  const float* bv = (const float*)d_in[10];
  const float* Wo = (const float*)d_in[11];
  const float* bo = (const float*)d_in[12];

  char* ws = (char*)d_ws;
  const size_t MB = 1024 * 1024;
  const bool big = ws_size >= 58 * MB;

  if (big) {
    u16* qb  = (u16*)(ws + 0 * MB);
    u16* kb  = (u16*)(ws + 8 * MB);
    u16* vb  = (u16*)(ws + 16 * MB);
    u16* wqb = (u16*)(ws + 24 * MB);
    u16* wkb = (u16*)(ws + 26 * MB);
    u16* wvb = (u16*)(ws + 28 * MB);
    u16* wob = (u16*)(ws + 30 * MB);
    u16* Qh  = (u16*)(ws + 32 * MB);
    u16* Kh  = (u16*)(ws + 40 * MB);
    u16* Vh  = (u16*)(ws + 48 * MB);
    u64* mbits = (u64*)(ws + 56 * MB);
    u16* ctx = qb;   // qb dead after gemm_qkv

    ConvArgs ca;
    ca.src[0] = q;  ca.dst[0] = qb;  ca.n4[0] = 1048576; ca.scale[0] = 1.f;
    ca.src[1] = k;  ca.dst[1] = kb;  ca.n4[1] = 1048576; ca.scale[1] = 1.f;
    ca.src[2] = v;  ca.dst[2] = vb;  ca.n4[2] = 1048576; ca.scale[2] = 1.f;
    ca.src[3] = Wq; ca.dst[3] = wqb; ca.n4[3] = 262144;  ca.scale[3] = 0.125f * L2E;
    ca.src[4] = Wk; ca.dst[4] = wkb; ca.n4[4] = 262144;  ca.scale[4] = 1.f;
    ca.src[5] = Wv; ca.dst[5] = wvb; ca.n4[5] = 262144;  ca.scale[5] = 1.f;
    ca.src[6] = Wo; ca.dst[6] = wob; ca.n4[6] = 262144;  ca.scale[6] = 1.f;
    convert_many<<<dim3(512, 7), 256, 0, stream>>>(ca);

    QkvArgsB ga;
    ga.A[0] = qb; ga.B[0] = wqb; ga.bias[0] = bq; ga.bscale[0] = 0.125f * L2E; ga.C[0] = Qh;
    ga.A[1] = kb; ga.B[1] = wkb; ga.bias[1] = bk; ga.bscale[1] = 1.f;          ga.C[1] = Kh;
    ga.A[2] = vb; ga.B[2] = wvb; ga.bias[2] = bv; ga.bscale[2] = 1.f;          ga.C[2] = Vh;
    ga.mask = (const unsigned*)am; ga.bits = mbits; ga.nmask = 8388608;
    gemm_qkv_bf<<<dim3(32, 8, 4), 256, 0, stream>>>(ga);   // z==3 packs the mask

    attn_kernel<<<512, 256, 0, stream>>>(Qh, Kh, Vh, mbits, hm, ctx);

    gemm_out<<<dim3(64, 8), 256, 0, stream>>>(ctx, wob, bo, q, (float*)d_out);
  } else {
    u16* Qh  = (u16*)(ws + 0 * MB);
    u16* Kh  = (u16*)(ws + 8 * MB);
    u16* Vh  = (u16*)(ws + 16 * MB);
    u16* wqb = (u16*)(ws + 24 * MB);
    u16* wkb = (u16*)(ws + 26 * MB);
    u16* wvb = (u16*)(ws + 28 * MB);
    u16* wob = (u16*)(ws + 30 * MB);
    u64* mbits = (u64*)(ws + 32 * MB);
    u16* ctx = (u16*)(ws + 33 * MB);

    ConvArgs ca;
    ca.src[0] = Wq; ca.dst[0] = wqb; ca.n4[0] = 262144; ca.scale[0] = 0.125f * L2E;
    ca.src[1] = Wk; ca.dst[1] = wkb; ca.n4[1] = 262144; ca.scale[1] = 1.f;
    ca.src[2] = Wv; ca.dst[2] = wvb; ca.n4[2] = 262144; ca.scale[2] = 1.f;
    ca.src[3] = Wo; ca.dst[3] = wob; ca.n4[3] = 262144; ca.scale[3] = 1.f;
    convert_many<<<dim3(256, 4), 256, 0, stream>>>(ca);

    mask_to_bits<<<2048, 256, 0, stream>>>((const unsigned int*)am, mbits, 8388608);

    QkvArgsF ga;
    ga.A[0] = q; ga.B[0] = wqb; ga.bias[0] = bq; ga.bscale[0] = 0.125f * L2E; ga.C[0] = Qh;
    ga.A[1] = k; ga.B[1] = wkb; ga.bias[1] = bk; ga.bscale[1] = 1.f;          ga.C[1] = Kh;
    ga.A[2] = v; ga.B[2] = wvb; ga.bias[2] = bv; ga.bscale[2] = 1.f;          ga.C[2] = Vh;
    gemm_qkv_f32<<<dim3(32, 8, 3), 256, 0, stream>>>(ga);

    attn_kernel<<<512, 256, 0, stream>>>(Qh, Kh, Vh, mbits, hm, ctx);

    gemm_out<<<dim3(64, 8), 256, 0, stream>>>(ctx, wob, bo, q, (float*)d_out);
  }
}

// Round 16
// 149.761 us; speedup vs baseline: 1.1992x; 1.1992x over previous
//
#include <hip/hip_runtime.h>

typedef unsigned short u16;
typedef unsigned long long u64;
typedef __attribute__((ext_vector_type(4))) float f32x4;
typedef __attribute__((ext_vector_type(8))) short s16x8;
typedef __attribute__((ext_vector_type(4))) short s16x4;
typedef __attribute__((ext_vector_type(4))) unsigned int u32x4;

#define LDS_LOAD16(gp, lp) __builtin_amdgcn_global_load_lds( \
    (__attribute__((address_space(1))) void*)(gp), \
    (__attribute__((address_space(3))) void*)(lp), 16, 0, 0)

#define MFMA16 __builtin_amdgcn_mfma_f32_16x16x32_bf16

constexpr float L2E = 1.44269504088896340736f;

__device__ __forceinline__ u16 f2bf(float x) {
  unsigned u = __float_as_uint(x);
  u += 0x7FFF + ((u >> 16) & 1);   // RNE
  return (u16)(u >> 16);
}

__device__ __forceinline__ unsigned cvtpk_bf16(float lo, float hi) {
  unsigned r;
  asm("v_cvt_pk_bf16_f32 %0, %1, %2" : "=v"(r) : "v"(lo), "v"(hi));
  return r;
}

// ---------------------------------------------------------------- convert
struct ConvArgs {
  const float* src[7];
  u16* dst[7];
  int n4[7];
  float scale[7];
};

__global__ __launch_bounds__(256) void convert_many(ConvArgs a) {
  const int arr = blockIdx.y;
  const f32x4* src = (const f32x4*)a.src[arr];
  u16* dst = a.dst[arr];
  const int n4 = a.n4[arr];
  const float sc = a.scale[arr];
  const int stride = gridDim.x * blockDim.x;
  for (int i = blockIdx.x * blockDim.x + threadIdx.x; i < n4; i += stride) {
    f32x4 v = src[i];
    s16x4 o;
#pragma unroll
    for (int j = 0; j < 4; ++j) o[j] = (short)f2bf(v[j] * sc);
    *(s16x4*)(dst + (size_t)i * 4) = o;
  }
}

// ---------------------------------------------------------------- mask -> bits
__global__ __launch_bounds__(256) void mask_to_bits(const unsigned int* __restrict__ m32,
                                                    u64* __restrict__ bits,
                                                    int n) {
  const int lane = threadIdx.x & 63;
  unsigned probe = m32[lane];
  bool bytemode = __any(probe > 1u);
  const int stride = gridDim.x * blockDim.x;
  for (int i = blockIdx.x * blockDim.x + threadIdx.x; i < n; i += stride) {
    bool v;
    if (bytemode) v = ((const unsigned char*)m32)[i] != 0;
    else          v = m32[i] != 0;
    u64 b = __ballot(v);
    if (lane == 0) bits[i >> 6] = b;
  }
}

// ---------------------------------------------------------------- QKV GEMM (bf16, T4 pipeline)
struct QkvArgsB {
  const u16* A[3];
  const u16* B[3];
  const float* bias[3];
  float bscale[3];
  u16* C[3];
};

__global__ __launch_bounds__(256) void gemm_qkv_bf(QkvArgsB a) {
  const int z = blockIdx.z;
  const u16* __restrict__ A = a.A[z];
  const u16* __restrict__ B = a.B[z];
  const float* __restrict__ bias = a.bias[z];
  const float bscale = a.bscale[z];
  u16* __restrict__ C = a.C[z];

  __shared__ u16 As[3][4096];
  __shared__ u16 Bs[3][4096];
  const int tid = threadIdx.x;
  const int lane = tid & 63;
  const int wave = tid >> 6;
  const int g = lane >> 4, c = lane & 15;
  const int g4 = g * 4;
  const int bx = blockIdx.x;
  const int row0 = (((bx & 7) << 2) | (bx >> 3)) * 128;   // XCD-chunked rows
  const int col0 = blockIdx.y * 128;
  const int wr = (wave >> 1) * 64, wc = (wave & 1) * 64;

  f32x4 acc[4][4] = {};

#define STAGE_QKV(p_, k0_) { _Pragma("unroll") \
    for (int i = 0; i < 2; ++i) { \
      int e = (i * 256 + tid) * 8; \
      LDS_LOAD16(A + (size_t)(row0 + (e >> 5)) * 1024 + (k0_) + (e & 31), As[p_] + e); \
      LDS_LOAD16(B + (size_t)(col0 + (e >> 5)) * 1024 + (k0_) + (e & 31), Bs[p_] + e); } }

  STAGE_QKV(0, 0);
  STAGE_QKV(1, 32);

  for (int s = 0; s < 32; ++s) {
    const int p = s % 3;
    if (s == 31) asm volatile("s_waitcnt vmcnt(0)" ::: "memory");
    else         asm volatile("s_waitcnt vmcnt(4)" ::: "memory");
    __builtin_amdgcn_s_barrier();
    __builtin_amdgcn_sched_barrier(0);
    if (s + 2 < 32) {
      const int np = (s + 2) % 3;
      STAGE_QKV(np, (s + 2) * 32);
    }
    s16x8 af[4], bf[4];
#pragma unroll
    for (int m = 0; m < 4; ++m) af[m] = *(const s16x8*)(As[p] + (wr + m * 16 + c) * 32 + g * 8);
#pragma unroll
    for (int n = 0; n < 4; ++n) bf[n] = *(const s16x8*)(Bs[p] + (wc + n * 16 + c) * 32 + g * 8);
#pragma unroll
    for (int m = 0; m < 4; ++m)
#pragma unroll
      for (int n = 0; n < 4; ++n)
        acc[m][n] = MFMA16(bf[n], af[m], acc[m][n], 0, 0, 0);   // swapped
  }

  f32x4 bv[4];
#pragma unroll
  for (int n = 0; n < 4; ++n) {
    bv[n] = *(const f32x4*)(bias + col0 + wc + n * 16 + g4);
#pragma unroll
    for (int r = 0; r < 4; ++r) bv[n][r] *= bscale;
  }
#pragma unroll
  for (int m = 0; m < 4; ++m)
#pragma unroll
    for (int n = 0; n < 4; ++n) {
      s16x4 o;
#pragma unroll
      for (int r = 0; r < 4; ++r) o[r] = (short)f2bf(acc[m][n][r] + bv[n][r]);
      *(s16x4*)(C + (size_t)(row0 + wr + m * 16 + c) * 1024 + col0 + wc + n * 16 + g4) = o;
    }
}

// ---------------------------------------------------------------- QKV GEMM (fp32 A, fallback)
struct QkvArgsF {
  const float* A[3];
  const u16* B[3];
  const float* bias[3];
  float bscale[3];
  u16* C[3];
};

__global__ __launch_bounds__(256) void gemm_qkv_f32(QkvArgsF a) {
  const int z = blockIdx.z;
  const float* __restrict__ A = a.A[z];
  const u16* __restrict__ B = a.B[z];
  const float* __restrict__ bias = a.bias[z];
  const float bscale = a.bscale[z];
  u16* __restrict__ C = a.C[z];

  __shared__ u16 As[2][4096];
  __shared__ u16 Bs[2][4096];
  const int tid = threadIdx.x;
  const int lane = tid & 63;
  const int wave = tid >> 6;
  const int g = lane >> 4, c = lane & 15;
  const int g4 = g * 4;
  const int row0 = blockIdx.x * 128;
  const int col0 = blockIdx.y * 128;
  const int wr = (wave >> 1) * 64, wc = (wave & 1) * 64;
  const int ra = tid >> 2;
  const int cca = (tid & 3) * 8;

  f32x4 acc[4][4] = {};
  f32x4 ar[2][2];
#pragma unroll
  for (int i = 0; i < 2; ++i) {
    ar[i][0] = *(const f32x4*)(A + (size_t)(row0 + i * 64 + ra) * 1024 + cca);
    ar[i][1] = *(const f32x4*)(A + (size_t)(row0 + i * 64 + ra) * 1024 + cca + 4);
  }

  for (int s = 0; s < 32; ++s) {
    const int p = s & 1;
    const int k0 = s * 32;
#pragma unroll
    for (int i = 0; i < 2; ++i) {
      unsigned w0 = cvtpk_bf16(ar[i][0][0], ar[i][0][1]);
      unsigned w1 = cvtpk_bf16(ar[i][0][2], ar[i][0][3]);
      unsigned w2 = cvtpk_bf16(ar[i][1][0], ar[i][1][1]);
      unsigned w3 = cvtpk_bf16(ar[i][1][2], ar[i][1][3]);
      union { u32x4 u; s16x8 v; } w;
      w.u = (u32x4){w0, w1, w2, w3};
      *(s16x8*)(As[p] + (i * 256 + tid) * 8) = w.v;
    }
    if (s < 31) {
#pragma unroll
      for (int i = 0; i < 2; ++i) {
        ar[i][0] = *(const f32x4*)(A + (size_t)(row0 + i * 64 + ra) * 1024 + k0 + 32 + cca);
        ar[i][1] = *(const f32x4*)(A + (size_t)(row0 + i * 64 + ra) * 1024 + k0 + 32 + cca + 4);
      }
    }
#pragma unroll
    for (int i = 0; i < 2; ++i) {
      int e = (i * 256 + tid) * 8;
      LDS_LOAD16(B + (size_t)(col0 + (e >> 5)) * 1024 + k0 + (e & 31), Bs[p] + e);
    }
    __syncthreads();

    s16x8 af[4], bf[4];
#pragma unroll
    for (int m = 0; m < 4; ++m) af[m] = *(const s16x8*)(As[p] + (wr + m * 16 + c) * 32 + g * 8);
#pragma unroll
    for (int n = 0; n < 4; ++n) bf[n] = *(const s16x8*)(Bs[p] + (wc + n * 16 + c) * 32 + g * 8);
#pragma unroll
    for (int m = 0; m < 4; ++m)
#pragma unroll
      for (int n = 0; n < 4; ++n)
        acc[m][n] = MFMA16(bf[n], af[m], acc[m][n], 0, 0, 0);
  }

  f32x4 bv[4];
#pragma unroll
  for (int n = 0; n < 4; ++n) {
    bv[n] = *(const f32x4*)(bias + col0 + wc + n * 16 + g4);
#pragma unroll
    for (int r = 0; r < 4; ++r) bv[n][r] *= bscale;
  }
#pragma unroll
  for (int m = 0; m < 4; ++m)
#pragma unroll
    for (int n = 0; n < 4; ++n) {
      s16x4 o;
#pragma unroll
      for (int r = 0; r < 4; ++r) o[r] = (short)f2bf(acc[m][n][r] + bv[n][r]);
      *(s16x4*)(C + (size_t)(row0 + wr + m * 16 + c) * 1024 + col0 + wc + n * 16 + g4) = o;
    }
}

// ---------------------------------------------------------------- out GEMM (T4 pipeline)
__global__ __launch_bounds__(256) void gemm_out(const u16* __restrict__ A,
                                                const u16* __restrict__ B,
                                                const float* __restrict__ bias,
                                                const float* __restrict__ resid,
                                                float* __restrict__ C) {
  __shared__ u16 As[3][2048];
  __shared__ u16 Bs[3][4096];
  const int tid = threadIdx.x;
  const int lane = tid & 63;
  const int wave = tid >> 6;
  const int g = lane >> 4, c = lane & 15;
  const int g4 = g * 4;
  const int bx = blockIdx.x;
  const int row0 = (((bx & 7) << 3) | (bx >> 3)) * 64;    // XCD-chunked rows
  const int col0 = blockIdx.y * 128;
  const int wr = (wave >> 1) * 32, wc = (wave & 1) * 64;

  f32x4 acc[2][4] = {};

#define STAGE_OUT(p_, k0_) { \
    LDS_LOAD16(A + (size_t)(row0 + (tid >> 2)) * 1024 + (k0_) + (tid & 3) * 8, As[p_] + tid * 8); \
    _Pragma("unroll") \
    for (int i = 0; i < 2; ++i) { \
      int e = (i * 256 + tid) * 8; \
      LDS_LOAD16(B + (size_t)(col0 + (e >> 5)) * 1024 + (k0_) + (e & 31), Bs[p_] + e); } }

  STAGE_OUT(0, 0);
  STAGE_OUT(1, 32);

  for (int s = 0; s < 32; ++s) {
    const int p = s % 3;
    if (s == 31) asm volatile("s_waitcnt vmcnt(0)" ::: "memory");
    else         asm volatile("s_waitcnt vmcnt(3)" ::: "memory");
    __builtin_amdgcn_s_barrier();
    __builtin_amdgcn_sched_barrier(0);
    if (s + 2 < 32) {
      const int np = (s + 2) % 3;
      STAGE_OUT(np, (s + 2) * 32);
    }
    s16x8 af[2], bf[4];
#pragma unroll
    for (int m = 0; m < 2; ++m) af[m] = *(const s16x8*)(As[p] + (wr + m * 16 + c) * 32 + g * 8);
#pragma unroll
    for (int n = 0; n < 4; ++n) bf[n] = *(const s16x8*)(Bs[p] + (wc + n * 16 + c) * 32 + g * 8);
#pragma unroll
    for (int m = 0; m < 2; ++m)
#pragma unroll
      for (int n = 0; n < 4; ++n)
        acc[m][n] = MFMA16(bf[n], af[m], acc[m][n], 0, 0, 0);
  }

  f32x4 bv[4];
#pragma unroll
  for (int n = 0; n < 4; ++n) bv[n] = *(const f32x4*)(bias + col0 + wc + n * 16 + g4);
#pragma unroll
  for (int m = 0; m < 2; ++m)
#pragma unroll
    for (int n = 0; n < 4; ++n) {
      size_t off = (size_t)(row0 + wr + m * 16 + c) * 1024 + col0 + wc + n * 16 + g4;
      f32x4 rv = *(const f32x4*)(resid + off);
      f32x4 o;
#pragma unroll
      for (int r = 0; r < 4; ++r) o[r] = acc[m][n][r] + bv[n][r] + rv[r];
      *(f32x4*)(C + off) = o;
    }
}

// ---------------------------------------------------------------- attention (proven 69 us)
// 128 q-rows/block, 2 q-subtiles/wave, grid 512 (2 blocks/CU). sigma-permuted
// V layout (8xb128 reads land in zero-shuffle pa k-order), v_perm staging
// pack, ones-MFMA denominator, literal-p x2 unroll, 1 barrier/iter.
constexpr float NEGV = -10000000.0f;

__global__ __launch_bounds__(256) void attn_kernel(const u16* __restrict__ Qh,
                                                   const u16* __restrict__ Kh,
                                                   const u16* __restrict__ Vh,
                                                   const u64* __restrict__ mbits,
                                                   const float* __restrict__ head_mask,
                                                   u16* __restrict__ ctx) {
  __shared__ u16 Ks[2][4096];      // d-chunked: [chunk(d/8)][key(64)][d%8]
  __shared__ u16 Vt[2][64 * 72];   // [d][sigma(key) ^ 8*(d>>3)], stride 72

  const int tid = threadIdx.x;
  const int lane = tid & 63;
  const int wave = tid >> 6;
  const int g = lane >> 4, c = lane & 15;
  const int g4 = g * 4;
  const int wid = (blockIdx.x & 7) * 64 + (blockIdx.x >> 3);
  const int qt = wid & 15;
  const int bh = wid >> 4;
  const int b = bh >> 4;
  const int h = bh & 15;
  const size_t rowbase = (size_t)b * 2048;
  const int D = 1024;

  s16x8 qf[2][2];
#pragma unroll
  for (int s = 0; s < 2; ++s) {
    const int qrow = qt * 128 + s * 64 + wave * 16 + c;
#pragma unroll
    for (int ks = 0; ks < 2; ++ks)
      qf[s][ks] = *(const s16x8*)(Qh + (rowbase + qrow) * D + h * 64 + ks * 32 + g * 8);
  }

  f32x4 accO[2][4] = {};
  f32x4 accSum[2] = {};            // ones-MFMA denominator; col q=c

  union { u32x4 u; s16x8 v; } onesu;
  onesu.u = (u32x4){0x3F803F80u, 0x3F803F80u, 0x3F803F80u, 0x3F803F80u};
  const s16x8 onesA = onesu.v;

  const u64* mrow0 = mbits + (rowbase + qt * 128 + 0 * 64 + wave * 16 + c) * 32;
  const u64* mrow1 = mbits + (rowbase + qt * 128 + 1 * 64 + wave * 16 + c) * 32;

  const int kkK = tid & 63;
  const int aV = tid >> 3;
  const int sV = tid & 7;
  const int dcV = sV * 8;
  // sigma(k): k=32K+16H+4G+J -> slot 32K+8G+4H+J  (pairs k=2a,2a+1 stay adjacent)
  const int k2 = 2 * aV;
  const int slotV = (k2 & 32) | (((k2 >> 2) & 3) << 3) | (((k2 >> 4) & 1) << 2) | (k2 & 3);
  const int colV = slotV ^ (8 * sV);

  const u16* Kbase = Kh + rowbase * D + h * 64;
  const u16* Vbase = Vh + rowbase * D + h * 64;

  s16x8 kreg[2], vreg[2];
#define LOADKV(kb_) { \
    kreg[0] = *(const s16x8*)(Kbase + (size_t)((kb_) + kkK) * D + wave * 8); \
    kreg[1] = *(const s16x8*)(Kbase + (size_t)((kb_) + kkK) * D + (4 + wave) * 8); \
    vreg[0] = *(const s16x8*)(Vbase + (size_t)((kb_) + k2) * D + dcV); \
    vreg[1] = *(const s16x8*)(Vbase + (size_t)((kb_) + k2 + 1) * D + dcV); }
#define WRITEKV(p_) { \
    *(s16x8*)(Ks[p_] + tid * 8) = kreg[0]; \
    *(s16x8*)(Ks[p_] + 2048 + tid * 8) = kreg[1]; \
    const unsigned* v0w = (const unsigned*)&vreg[0]; \
    const unsigned* v1w = (const unsigned*)&vreg[1]; \
    _Pragma("unroll") \
    for (int j = 0; j < 8; ++j) { \
      unsigned pk = __builtin_amdgcn_perm(v1w[j >> 1], v0w[j >> 1], \
                                          (j & 1) ? 0x07060302u : 0x05040100u); \
      *(unsigned*)(Vt[p_] + (dcV + j) * 72 + colV) = pk; } }

  LOADKV(0);
  WRITEKV(0);
  LOADKV(64);
  __syncthreads();

#define ATTN_ITER(p_, it_) { \
    const int it = (it_); \
    if (it < 31) WRITEKV(p_ ^ 1); \
    if (it < 30) LOADKV((it + 2) * 64); \
    f32x4 accS[2][4]; \
    _Pragma("unroll") \
    for (int t = 0; t < 4; ++t) { \
      s16x8 kf0 = *(const s16x8*)(Ks[p_] + ((0 + g) * 64 + t * 16 + c) * 8); \
      s16x8 kf1 = *(const s16x8*)(Ks[p_] + ((4 + g) * 64 + t * 16 + c) * 8); \
      f32x4 z0 = {0.f, 0.f, 0.f, 0.f}; \
      z0 = MFMA16(kf0, qf[0][0], z0, 0, 0, 0); \
      accS[0][t] = MFMA16(kf1, qf[0][1], z0, 0, 0, 0); \
      f32x4 z1 = {0.f, 0.f, 0.f, 0.f}; \
      z1 = MFMA16(kf0, qf[1][0], z1, 0, 0, 0); \
      accS[1][t] = MFMA16(kf1, qf[1][1], z1, 0, 0, 0); \
    } \
    s16x8 vbr[4][2]; \
    _Pragma("unroll") \
    for (int d0 = 0; d0 < 4; ++d0) { \
      const int dd = d0 * 16 + c; \
      const int sw8 = (d0 * 2 + (c >> 3)) * 8; \
      _Pragma("unroll") \
      for (int ks = 0; ks < 2; ++ks) \
        vbr[d0][ks] = *(const s16x8*)(Vt[p_] + dd * 72 + ((ks * 32 + g * 8) ^ sw8)); \
    } \
    s16x8 pa[2][2]; \
    _Pragma("unroll") \
    for (int s = 0; s < 2; ++s) { \
      u64 mw = (s == 0 ? mrow0 : mrow1)[it]; \
      u64 sh = mw >> g4; \
      unsigned mlo = (unsigned)sh, mhi = (unsigned)(sh >> 32); \
      unsigned pk0[4], pk1[4]; \
      _Pragma("unroll") \
      for (int t = 0; t < 4; ++t) { \
        unsigned msrc = (t < 2) ? mlo : mhi; \
        _Pragma("unroll") \
        for (int r = 0; r < 4; ++r) { \
          float sv = accS[s][t][r]; \
          if ((msrc >> ((t & 1) * 16 + r)) & 1) sv = NEGV; \
          float pv; \
          asm("v_exp_f32 %0, %1" : "=v"(pv) : "v"(sv)); \
          accS[s][t][r] = pv; \
        } \
        pk0[t] = cvtpk_bf16(accS[s][t][0], accS[s][t][1]); \
        pk1[t] = cvtpk_bf16(accS[s][t][2], accS[s][t][3]); \
      } \
      _Pragma("unroll") \
      for (int ks = 0; ks < 2; ++ks) { \
        union { u32x4 u; s16x8 v; } w; \
        w.u = (u32x4){pk0[2 * ks], pk1[2 * ks], pk0[2 * ks + 1], pk1[2 * ks + 1]}; \
        pa[s][ks] = w.v; \
      } \
    } \
    _Pragma("unroll") \
    for (int d0 = 0; d0 < 4; ++d0) \
      _Pragma("unroll") \
      for (int ks = 0; ks < 2; ++ks) { \
        accO[0][d0] = MFMA16(vbr[d0][ks], pa[0][ks], accO[0][d0], 0, 0, 0); \
        accO[1][d0] = MFMA16(vbr[d0][ks], pa[1][ks], accO[1][d0], 0, 0, 0); \
      } \
    _Pragma("unroll") \
    for (int ks = 0; ks < 2; ++ks) { \
      accSum[0] = MFMA16(onesA, pa[0][ks], accSum[0], 0, 0, 0); \
      accSum[1] = MFMA16(onesA, pa[1][ks], accSum[1], 0, 0, 0); \
    } \
    __syncthreads(); }

  for (int it2 = 0; it2 < 16; ++it2) {
    ATTN_ITER(0, 2 * it2);
    ATTN_ITER(1, 2 * it2 + 1);
  }

  const float hm = head_mask[0];
#pragma unroll
  for (int s = 0; s < 2; ++s) {
    float inv = hm / accSum[s][0];
    const int qrow = qt * 128 + s * 64 + wave * 16 + c;
#pragma unroll
    for (int d0 = 0; d0 < 4; ++d0) {
      s16x4 o;
#pragma unroll
      for (int r = 0; r < 4; ++r) o[r] = (short)f2bf(accO[s][d0][r] * inv);
      *(s16x4*)(ctx + (rowbase + qrow) * D + h * 64 + d0 * 16 + g4) = o;
    }
  }
}

// ---------------------------------------------------------------- launch
extern "C" void kernel_launch(void* const* d_in, const int* in_sizes, int n_in,
                              void* d_out, int out_size, void* d_ws, size_t ws_size,
                              hipStream_t stream) {
  const float* q  = (const float*)d_in[0];
  const float* k  = (const float*)d_in[1];
  const float* v  = (const float*)d_in[2];
  const void*  am = d_in[3];
  const float* hm = (const float*)d_in[4];
  const float* Wq = (const float*)d_in[5];
  const float* bq = (const float*)d_in[6];
  const float* Wk = (const float*)d_in[7];
  const float* bk = (const float*)d_in[8];
  const float* Wv = (const float*)d_in[9];
  const float* bv = (const float*)d_in[10];
  const float* Wo = (const float*)d_in[11];
  const float* bo = (const float*)d_in[12];

  char* ws = (char*)d_ws;
  const size_t MB = 1024 * 1024;
  const bool big = ws_size >= 58 * MB;

  if (big) {
    u16* qb  = (u16*)(ws + 0 * MB);
    u16* kb  = (u16*)(ws + 8 * MB);
    u16* vb  = (u16*)(ws + 16 * MB);
    u16* wqb = (u16*)(ws + 24 * MB);
    u16* wkb = (u16*)(ws + 26 * MB);
    u16* wvb = (u16*)(ws + 28 * MB);
    u16* wob = (u16*)(ws + 30 * MB);
    u16* Qh  = (u16*)(ws + 32 * MB);
    u16* Kh  = (u16*)(ws + 40 * MB);
    u16* Vh  = (u16*)(ws + 48 * MB);
    u64* mbits = (u64*)(ws + 56 * MB);
    u16* ctx = qb;   // qb dead after gemm_qkv

    ConvArgs ca;
    ca.src[0] = q;  ca.dst[0] = qb;  ca.n4[0] = 1048576; ca.scale[0] = 1.f;
    ca.src[1] = k;  ca.dst[1] = kb;  ca.n4[1] = 1048576; ca.scale[1] = 1.f;
    ca.src[2] = v;  ca.dst[2] = vb;  ca.n4[2] = 1048576; ca.scale[2] = 1.f;
    ca.src[3] = Wq; ca.dst[3] = wqb; ca.n4[3] = 262144;  ca.scale[3] = 0.125f * L2E;
    ca.src[4] = Wk; ca.dst[4] = wkb; ca.n4[4] = 262144;  ca.scale[4] = 1.f;
    ca.src[5] = Wv; ca.dst[5] = wvb; ca.n4[5] = 262144;  ca.scale[5] = 1.f;
    ca.src[6] = Wo; ca.dst[6] = wob; ca.n4[6] = 262144;  ca.scale[6] = 1.f;
    convert_many<<<dim3(512, 7), 256, 0, stream>>>(ca);

    mask_to_bits<<<2048, 256, 0, stream>>>((const unsigned int*)am, mbits, 8388608);

    QkvArgsB ga;
    ga.A[0] = qb; ga.B[0] = wqb; ga.bias[0] = bq; ga.bscale[0] = 0.125f * L2E; ga.C[0] = Qh;
    ga.A[1] = kb; ga.B[1] = wkb; ga.bias[1] = bk; ga.bscale[1] = 1.f;          ga.C[1] = Kh;
    ga.A[2] = vb; ga.B[2] = wvb; ga.bias[2] = bv; ga.bscale[2] = 1.f;          ga.C[2] = Vh;
    gemm_qkv_bf<<<dim3(32, 8, 3), 256, 0, stream>>>(ga);

    attn_kernel<<<512, 256, 0, stream>>>(Qh, Kh, Vh, mbits, hm, ctx);

    gemm_out<<<dim3(64, 8), 256, 0, stream>>>(ctx, wob, bo, q, (float*)d_out);
  } else {
    u16* Qh  = (u16*)(ws + 0 * MB);
    u16* Kh  = (u16*)(ws + 8 * MB);
    u16* Vh  = (u16*)(ws + 16 * MB);
    u16* wqb = (u16*)(ws + 24 * MB);
    u16* wkb = (u16*)(ws + 26 * MB);
    u16* wvb = (u16*)(ws + 28 * MB);
    u16* wob = (u16*)(ws + 30 * MB);
    u64* mbits = (u64*)(ws + 32 * MB);
    u16* ctx = (u16*)(ws + 33 * MB);

    ConvArgs ca;
    ca.src[0] = Wq; ca.dst[0] = wqb; ca.n4[0] = 262144; ca.scale[0] = 0.125f * L2E;
    ca.src[1] = Wk; ca.dst[1] = wkb; ca.n4[1] = 262144; ca.scale[1] = 1.f;
    ca.src[2] = Wv; ca.dst[2] = wvb; ca.n4[2] = 262144; ca.scale[2] = 1.f;
    ca.src[3] = Wo; ca.dst[3] = wob; ca.n4[3] = 262144; ca.scale[3] = 1.f;
    convert_many<<<dim3(256, 4), 256, 0, stream>>>(ca);

    mask_to_bits<<<2048, 256, 0, stream>>>((const unsigned int*)am, mbits, 8388608);

    QkvArgsF ga;
    ga.A[0] = q; ga.B[0] = wqb; ga.bias[0] = bq; ga.bscale[0] = 0.125f * L2E; ga.C[0] = Qh;
    ga.A[1] = k; ga.B[1] = wkb; ga.bias[1] = bk; ga.bscale[1] = 1.f;          ga.C[1] = Kh;
    ga.A[2] = v; ga.B[2] = wvb; ga.bias[2] = bv; ga.bscale[2] = 1.f;          ga.C[2] = Vh;
    gemm_qkv_f32<<<dim3(32, 8, 3), 256, 0, stream>>>(ga);

    attn_kernel<<<512, 256, 0, stream>>>(Qh, Kh, Vh, mbits, hm, ctx);

    gemm_out<<<dim3(64, 8), 256, 0, stream>>>(ctx, wob, bo, q, (float*)d_out);
  }
}

// Round 17
// 146.554 us; speedup vs baseline: 1.2254x; 1.0219x over previous
//
#include <hip/hip_runtime.h>

typedef unsigned short u16;
typedef unsigned long long u64;
typedef __attribute__((ext_vector_type(4))) float f32x4;
typedef __attribute__((ext_vector_type(8))) short s16x8;
typedef __attribute__((ext_vector_type(4))) short s16x4;
typedef __attribute__((ext_vector_type(4))) unsigned int u32x4;

#define LDS_LOAD16(gp, lp) __builtin_amdgcn_global_load_lds( \
    (__attribute__((address_space(1))) void*)(gp), \
    (__attribute__((address_space(3))) void*)(lp), 16, 0, 0)

#define MFMA16 __builtin_amdgcn_mfma_f32_16x16x32_bf16

constexpr float L2E = 1.44269504088896340736f;

__device__ __forceinline__ u16 f2bf(float x) {
  unsigned u = __float_as_uint(x);
  u += 0x7FFF + ((u >> 16) & 1);   // RNE
  return (u16)(u >> 16);
}

__device__ __forceinline__ unsigned cvtpk_bf16(float lo, float hi) {
  unsigned r;
  asm("v_cvt_pk_bf16_f32 %0, %1, %2" : "=v"(r) : "v"(lo), "v"(hi));
  return r;
}

// ---------------------------------------------------------------- convert
struct ConvArgs {
  const float* src[7];
  u16* dst[7];
  int n4[7];
  float scale[7];
};

__global__ __launch_bounds__(256) void convert_many(ConvArgs a) {
  const int arr = blockIdx.y;
  const f32x4* src = (const f32x4*)a.src[arr];
  u16* dst = a.dst[arr];
  const int n4 = a.n4[arr];
  const float sc = a.scale[arr];
  const int stride = gridDim.x * blockDim.x;
  for (int i = blockIdx.x * blockDim.x + threadIdx.x; i < n4; i += stride) {
    f32x4 v = src[i];
    s16x4 o;
#pragma unroll
    for (int j = 0; j < 4; ++j) o[j] = (short)f2bf(v[j] * sc);
    *(s16x4*)(dst + (size_t)i * 4) = o;
  }
}

// ---------------------------------------------------------------- mask -> bits
__global__ __launch_bounds__(256) void mask_to_bits(const unsigned int* __restrict__ m32,
                                                    u64* __restrict__ bits,
                                                    int n) {
  const int lane = threadIdx.x & 63;
  unsigned probe = m32[lane];
  bool bytemode = __any(probe > 1u);
  const int stride = gridDim.x * blockDim.x;
  for (int i = blockIdx.x * blockDim.x + threadIdx.x; i < n; i += stride) {
    bool v;
    if (bytemode) v = ((const unsigned char*)m32)[i] != 0;
    else          v = m32[i] != 0;
    u64 b = __ballot(v);
    if (lane == 0) bits[i >> 6] = b;
  }
}

// ---------------------------------------------------------------- QKV GEMM (bf16, T4 pipeline)
struct QkvArgsB {
  const u16* A[3];
  const u16* B[3];
  const float* bias[3];
  float bscale[3];
  u16* C[3];
};

__global__ __launch_bounds__(256) void gemm_qkv_bf(QkvArgsB a) {
  const int z = blockIdx.z;
  const u16* __restrict__ A = a.A[z];
  const u16* __restrict__ B = a.B[z];
  const float* __restrict__ bias = a.bias[z];
  const float bscale = a.bscale[z];
  u16* __restrict__ C = a.C[z];

  __shared__ u16 As[3][4096];
  __shared__ u16 Bs[3][4096];
  const int tid = threadIdx.x;
  const int lane = tid & 63;
  const int wave = tid >> 6;
  const int g = lane >> 4, c = lane & 15;
  const int g4 = g * 4;
  const int bx = blockIdx.x;
  const int row0 = (((bx & 7) << 2) | (bx >> 3)) * 128;   // XCD-chunked rows
  const int col0 = blockIdx.y * 128;
  const int wr = (wave >> 1) * 64, wc = (wave & 1) * 64;

  f32x4 acc[4][4] = {};

#define STAGE_QKV(p_, k0_) { _Pragma("unroll") \
    for (int i = 0; i < 2; ++i) { \
      int e = (i * 256 + tid) * 8; \
      LDS_LOAD16(A + (size_t)(row0 + (e >> 5)) * 1024 + (k0_) + (e & 31), As[p_] + e); \
      LDS_LOAD16(B + (size_t)(col0 + (e >> 5)) * 1024 + (k0_) + (e & 31), Bs[p_] + e); } }

  STAGE_QKV(0, 0);
  STAGE_QKV(1, 32);

  for (int s = 0; s < 32; ++s) {
    const int p = s % 3;
    if (s == 31) asm volatile("s_waitcnt vmcnt(0)" ::: "memory");
    else         asm volatile("s_waitcnt vmcnt(4)" ::: "memory");
    __builtin_amdgcn_s_barrier();
    __builtin_amdgcn_sched_barrier(0);
    if (s + 2 < 32) {
      const int np = (s + 2) % 3;
      STAGE_QKV(np, (s + 2) * 32);
    }
    s16x8 af[4], bf[4];
#pragma unroll
    for (int m = 0; m < 4; ++m) af[m] = *(const s16x8*)(As[p] + (wr + m * 16 + c) * 32 + g * 8);
#pragma unroll
    for (int n = 0; n < 4; ++n) bf[n] = *(const s16x8*)(Bs[p] + (wc + n * 16 + c) * 32 + g * 8);
#pragma unroll
    for (int m = 0; m < 4; ++m)
#pragma unroll
      for (int n = 0; n < 4; ++n)
        acc[m][n] = MFMA16(bf[n], af[m], acc[m][n], 0, 0, 0);   // swapped
  }

  f32x4 bv[4];
#pragma unroll
  for (int n = 0; n < 4; ++n) {
    bv[n] = *(const f32x4*)(bias + col0 + wc + n * 16 + g4);
#pragma unroll
    for (int r = 0; r < 4; ++r) bv[n][r] *= bscale;
  }
#pragma unroll
  for (int m = 0; m < 4; ++m)
#pragma unroll
    for (int n = 0; n < 4; ++n) {
      s16x4 o;
#pragma unroll
      for (int r = 0; r < 4; ++r) o[r] = (short)f2bf(acc[m][n][r] + bv[n][r]);
      *(s16x4*)(C + (size_t)(row0 + wr + m * 16 + c) * 1024 + col0 + wc + n * 16 + g4) = o;
    }
}

// ---------------------------------------------------------------- QKV GEMM (fp32 A, fallback)
struct QkvArgsF {
  const float* A[3];
  const u16* B[3];
  const float* bias[3];
  float bscale[3];
  u16* C[3];
};

__global__ __launch_bounds__(256) void gemm_qkv_f32(QkvArgsF a) {
  const int z = blockIdx.z;
  const float* __restrict__ A = a.A[z];
  const u16* __restrict__ B = a.B[z];
  const float* __restrict__ bias = a.bias[z];
  const float bscale = a.bscale[z];
  u16* __restrict__ C = a.C[z];

  __shared__ u16 As[2][4096];
  __shared__ u16 Bs[2][4096];
  const int tid = threadIdx.x;
  const int lane = tid & 63;
  const int wave = tid >> 6;
  const int g = lane >> 4, c = lane & 15;
  const int g4 = g * 4;
  const int row0 = blockIdx.x * 128;
  const int col0 = blockIdx.y * 128;
  const int wr = (wave >> 1) * 64, wc = (wave & 1) * 64;
  const int ra = tid >> 2;
  const int cca = (tid & 3) * 8;

  f32x4 acc[4][4] = {};
  f32x4 ar[2][2];
#pragma unroll
  for (int i = 0; i < 2; ++i) {
    ar[i][0] = *(const f32x4*)(A + (size_t)(row0 + i * 64 + ra) * 1024 + cca);
    ar[i][1] = *(const f32x4*)(A + (size_t)(row0 + i * 64 + ra) * 1024 + cca + 4);
  }

  for (int s = 0; s < 32; ++s) {
    const int p = s & 1;
    const int k0 = s * 32;
#pragma unroll
    for (int i = 0; i < 2; ++i) {
      unsigned w0 = cvtpk_bf16(ar[i][0][0], ar[i][0][1]);
      unsigned w1 = cvtpk_bf16(ar[i][0][2], ar[i][0][3]);
      unsigned w2 = cvtpk_bf16(ar[i][1][0], ar[i][1][1]);
      unsigned w3 = cvtpk_bf16(ar[i][1][2], ar[i][1][3]);
      union { u32x4 u; s16x8 v; } w;
      w.u = (u32x4){w0, w1, w2, w3};
      *(s16x8*)(As[p] + (i * 256 + tid) * 8) = w.v;
    }
    if (s < 31) {
#pragma unroll
      for (int i = 0; i < 2; ++i) {
        ar[i][0] = *(const f32x4*)(A + (size_t)(row0 + i * 64 + ra) * 1024 + k0 + 32 + cca);
        ar[i][1] = *(const f32x4*)(A + (size_t)(row0 + i * 64 + ra) * 1024 + k0 + 32 + cca + 4);
      }
    }
#pragma unroll
    for (int i = 0; i < 2; ++i) {
      int e = (i * 256 + tid) * 8;
      LDS_LOAD16(B + (size_t)(col0 + (e >> 5)) * 1024 + k0 + (e & 31), Bs[p] + e);
    }
    __syncthreads();

    s16x8 af[4], bf[4];
#pragma unroll
    for (int m = 0; m < 4; ++m) af[m] = *(const s16x8*)(As[p] + (wr + m * 16 + c) * 32 + g * 8);
#pragma unroll
    for (int n = 0; n < 4; ++n) bf[n] = *(const s16x8*)(Bs[p] + (wc + n * 16 + c) * 32 + g * 8);
#pragma unroll
    for (int m = 0; m < 4; ++m)
#pragma unroll
      for (int n = 0; n < 4; ++n)
        acc[m][n] = MFMA16(bf[n], af[m], acc[m][n], 0, 0, 0);
  }

  f32x4 bv[4];
#pragma unroll
  for (int n = 0; n < 4; ++n) {
    bv[n] = *(const f32x4*)(bias + col0 + wc + n * 16 + g4);
#pragma unroll
    for (int r = 0; r < 4; ++r) bv[n][r] *= bscale;
  }
#pragma unroll
  for (int m = 0; m < 4; ++m)
#pragma unroll
    for (int n = 0; n < 4; ++n) {
      s16x4 o;
#pragma unroll
      for (int r = 0; r < 4; ++r) o[r] = (short)f2bf(acc[m][n][r] + bv[n][r]);
      *(s16x4*)(C + (size_t)(row0 + wr + m * 16 + c) * 1024 + col0 + wc + n * 16 + g4) = o;
    }
}

// ---------------------------------------------------------------- out GEMM (T4 pipeline)
__global__ __launch_bounds__(256) void gemm_out(const u16* __restrict__ A,
                                                const u16* __restrict__ B,
                                                const float* __restrict__ bias,
                                                const float* __restrict__ resid,
                                                float* __restrict__ C) {
  __shared__ u16 As[3][2048];
  __shared__ u16 Bs[3][4096];
  const int tid = threadIdx.x;
  const int lane = tid & 63;
  const int wave = tid >> 6;
  const int g = lane >> 4, c = lane & 15;
  const int g4 = g * 4;
  const int bx = blockIdx.x;
  const int row0 = (((bx & 7) << 3) | (bx >> 3)) * 64;    // XCD-chunked rows
  const int col0 = blockIdx.y * 128;
  const int wr = (wave >> 1) * 32, wc = (wave & 1) * 64;

  f32x4 acc[2][4] = {};

#define STAGE_OUT(p_, k0_) { \
    LDS_LOAD16(A + (size_t)(row0 + (tid >> 2)) * 1024 + (k0_) + (tid & 3) * 8, As[p_] + tid * 8); \
    _Pragma("unroll") \
    for (int i = 0; i < 2; ++i) { \
      int e = (i * 256 + tid) * 8; \
      LDS_LOAD16(B + (size_t)(col0 + (e >> 5)) * 1024 + (k0_) + (e & 31), Bs[p_] + e); } }

  STAGE_OUT(0, 0);
  STAGE_OUT(1, 32);

  for (int s = 0; s < 32; ++s) {
    const int p = s % 3;
    if (s == 31) asm volatile("s_waitcnt vmcnt(0)" ::: "memory");
    else         asm volatile("s_waitcnt vmcnt(3)" ::: "memory");
    __builtin_amdgcn_s_barrier();
    __builtin_amdgcn_sched_barrier(0);
    if (s + 2 < 32) {
      const int np = (s + 2) % 3;
      STAGE_OUT(np, (s + 2) * 32);
    }
    s16x8 af[2], bf[4];
#pragma unroll
    for (int m = 0; m < 2; ++m) af[m] = *(const s16x8*)(As[p] + (wr + m * 16 + c) * 32 + g * 8);
#pragma unroll
    for (int n = 0; n < 4; ++n) bf[n] = *(const s16x8*)(Bs[p] + (wc + n * 16 + c) * 32 + g * 8);
#pragma unroll
    for (int m = 0; m < 2; ++m)
#pragma unroll
      for (int n = 0; n < 4; ++n)
        acc[m][n] = MFMA16(bf[n], af[m], acc[m][n], 0, 0, 0);
  }

  f32x4 bv[4];
#pragma unroll
  for (int n = 0; n < 4; ++n) bv[n] = *(const f32x4*)(bias + col0 + wc + n * 16 + g4);
#pragma unroll
  for (int m = 0; m < 2; ++m)
#pragma unroll
    for (int n = 0; n < 4; ++n) {
      size_t off = (size_t)(row0 + wr + m * 16 + c) * 1024 + col0 + wc + n * 16 + g4;
      f32x4 rv = *(const f32x4*)(resid + off);
      f32x4 o;
#pragma unroll
      for (int r = 0; r < 4; ++r) o[r] = acc[m][n][r] + bv[n][r] + rv[r];
      *(f32x4*)(C + off) = o;
    }
}

// ---------------------------------------------------------------- attention
// R10 structure + counted barrier: the per-iter __syncthreads drained
// vmcnt(0), forcibly waiting on the it+2 reg-prefetch issued this iter.
// Cross-wave correctness only needs lgkmcnt(0) (LDS writes visible); the
// global loads are per-lane private and guarded by data-dependency waits.
constexpr float NEGV = -10000000.0f;

__global__ __launch_bounds__(256) void attn_kernel(const u16* __restrict__ Qh,
                                                   const u16* __restrict__ Kh,
                                                   const u16* __restrict__ Vh,
                                                   const u64* __restrict__ mbits,
                                                   const float* __restrict__ head_mask,
                                                   u16* __restrict__ ctx) {
  __shared__ u16 Ks[2][4096];      // d-chunked: [chunk(d/8)][key(64)][d%8]
  __shared__ u16 Vt[2][64 * 72];   // [d][sigma(key) ^ 8*(d>>3)], stride 72

  const int tid = threadIdx.x;
  const int lane = tid & 63;
  const int wave = tid >> 6;
  const int g = lane >> 4, c = lane & 15;
  const int g4 = g * 4;
  const int wid = (blockIdx.x & 7) * 64 + (blockIdx.x >> 3);
  const int qt = wid & 15;
  const int bh = wid >> 4;
  const int b = bh >> 4;
  const int h = bh & 15;
  const size_t rowbase = (size_t)b * 2048;
  const int D = 1024;

  s16x8 qf[2][2];
#pragma unroll
  for (int s = 0; s < 2; ++s) {
    const int qrow = qt * 128 + s * 64 + wave * 16 + c;
#pragma unroll
    for (int ks = 0; ks < 2; ++ks)
      qf[s][ks] = *(const s16x8*)(Qh + (rowbase + qrow) * D + h * 64 + ks * 32 + g * 8);
  }

  f32x4 accO[2][4] = {};
  f32x4 accSum[2] = {};            // ones-MFMA denominator; col q=c

  union { u32x4 u; s16x8 v; } onesu;
  onesu.u = (u32x4){0x3F803F80u, 0x3F803F80u, 0x3F803F80u, 0x3F803F80u};
  const s16x8 onesA = onesu.v;

  const u64* mrow0 = mbits + (rowbase + qt * 128 + 0 * 64 + wave * 16 + c) * 32;
  const u64* mrow1 = mbits + (rowbase + qt * 128 + 1 * 64 + wave * 16 + c) * 32;

  const int kkK = tid & 63;
  const int aV = tid >> 3;
  const int sV = tid & 7;
  const int dcV = sV * 8;
  // sigma(k): k=32K+16H+4G+J -> slot 32K+8G+4H+J  (pairs k=2a,2a+1 stay adjacent)
  const int k2 = 2 * aV;
  const int slotV = (k2 & 32) | (((k2 >> 2) & 3) << 3) | (((k2 >> 4) & 1) << 2) | (k2 & 3);
  const int colV = slotV ^ (8 * sV);

  const u16* Kbase = Kh + rowbase * D + h * 64;
  const u16* Vbase = Vh + rowbase * D + h * 64;

  s16x8 kreg[2], vreg[2];
#define LOADKV(kb_) { \
    kreg[0] = *(const s16x8*)(Kbase + (size_t)((kb_) + kkK) * D + wave * 8); \
    kreg[1] = *(const s16x8*)(Kbase + (size_t)((kb_) + kkK) * D + (4 + wave) * 8); \
    vreg[0] = *(const s16x8*)(Vbase + (size_t)((kb_) + k2) * D + dcV); \
    vreg[1] = *(const s16x8*)(Vbase + (size_t)((kb_) + k2 + 1) * D + dcV); }
#define WRITEKV(p_) { \
    *(s16x8*)(Ks[p_] + tid * 8) = kreg[0]; \
    *(s16x8*)(Ks[p_] + 2048 + tid * 8) = kreg[1]; \
    const unsigned* v0w = (const unsigned*)&vreg[0]; \
    const unsigned* v1w = (const unsigned*)&vreg[1]; \
    _Pragma("unroll") \
    for (int j = 0; j < 8; ++j) { \
      unsigned pk = __builtin_amdgcn_perm(v1w[j >> 1], v0w[j >> 1], \
                                          (j & 1) ? 0x07060302u : 0x05040100u); \
      *(unsigned*)(Vt[p_] + (dcV + j) * 72 + colV) = pk; } }

  LOADKV(0);
  WRITEKV(0);
  LOADKV(64);
  __syncthreads();

#define ATTN_ITER(p_, it_) { \
    const int it = (it_); \
    if (it < 31) WRITEKV(p_ ^ 1); \
    if (it < 30) LOADKV((it + 2) * 64); \
    f32x4 accS[2][4]; \
    _Pragma("unroll") \
    for (int t = 0; t < 4; ++t) { \
      s16x8 kf0 = *(const s16x8*)(Ks[p_] + ((0 + g) * 64 + t * 16 + c) * 8); \
      s16x8 kf1 = *(const s16x8*)(Ks[p_] + ((4 + g) * 64 + t * 16 + c) * 8); \
      f32x4 z0 = {0.f, 0.f, 0.f, 0.f}; \
      z0 = MFMA16(kf0, qf[0][0], z0, 0, 0, 0); \
      accS[0][t] = MFMA16(kf1, qf[0][1], z0, 0, 0, 0); \
      f32x4 z1 = {0.f, 0.f, 0.f, 0.f}; \
      z1 = MFMA16(kf0, qf[1][0], z1, 0, 0, 0); \
      accS[1][t] = MFMA16(kf1, qf[1][1], z1, 0, 0, 0); \
    } \
    s16x8 vbr[4][2]; \
    _Pragma("unroll") \
    for (int d0 = 0; d0 < 4; ++d0) { \
      const int dd = d0 * 16 + c; \
      const int sw8 = (d0 * 2 + (c >> 3)) * 8; \
      _Pragma("unroll") \
      for (int ks = 0; ks < 2; ++ks) \
        vbr[d0][ks] = *(const s16x8*)(Vt[p_] + dd * 72 + ((ks * 32 + g * 8) ^ sw8)); \
    } \
    s16x8 pa[2][2]; \
    _Pragma("unroll") \
    for (int s = 0; s < 2; ++s) { \
      u64 mw = (s == 0 ? mrow0 : mrow1)[it]; \
      u64 sh = mw >> g4; \
      unsigned mlo = (unsigned)sh, mhi = (unsigned)(sh >> 32); \
      unsigned pk0[4], pk1[4]; \
      _Pragma("unroll") \
      for (int t = 0; t < 4; ++t) { \
        unsigned msrc = (t < 2) ? mlo : mhi; \
        _Pragma("unroll") \
        for (int r = 0; r < 4; ++r) { \
          float sv = accS[s][t][r]; \
          if ((msrc >> ((t & 1) * 16 + r)) & 1) sv = NEGV; \
          float pv; \
          asm("v_exp_f32 %0, %1" : "=v"(pv) : "v"(sv)); \
          accS[s][t][r] = pv; \
        } \
        pk0[t] = cvtpk_bf16(accS[s][t][0], accS[s][t][1]); \
        pk1[t] = cvtpk_bf16(accS[s][t][2], accS[s][t][3]); \
      } \
      _Pragma("unroll") \
      for (int ks = 0; ks < 2; ++ks) { \
        union { u32x4 u; s16x8 v; } w; \
        w.u = (u32x4){pk0[2 * ks], pk1[2 * ks], pk0[2 * ks + 1], pk1[2 * ks + 1]}; \
        pa[s][ks] = w.v; \
      } \
    } \
    _Pragma("unroll") \
    for (int d0 = 0; d0 < 4; ++d0) \
      _Pragma("unroll") \
      for (int ks = 0; ks < 2; ++ks) { \
        accO[0][d0] = MFMA16(vbr[d0][ks], pa[0][ks], accO[0][d0], 0, 0, 0); \
        accO[1][d0] = MFMA16(vbr[d0][ks], pa[1][ks], accO[1][d0], 0, 0, 0); \
      } \
    _Pragma("unroll") \
    for (int ks = 0; ks < 2; ++ks) { \
      accSum[0] = MFMA16(onesA, pa[0][ks], accSum[0], 0, 0, 0); \
      accSum[1] = MFMA16(onesA, pa[1][ks], accSum[1], 0, 0, 0); \
    } \
    asm volatile("s_waitcnt lgkmcnt(0)" ::: "memory"); \
    __builtin_amdgcn_s_barrier(); \
    __builtin_amdgcn_sched_barrier(0); }

  for (int it2 = 0; it2 < 16; ++it2) {
    ATTN_ITER(0, 2 * it2);
    ATTN_ITER(1, 2 * it2 + 1);
  }

  const float hm = head_mask[0];
#pragma unroll
  for (int s = 0; s < 2; ++s) {
    float inv = hm / accSum[s][0];
    const int qrow = qt * 128 + s * 64 + wave * 16 + c;
#pragma unroll
    for (int d0 = 0; d0 < 4; ++d0) {
      s16x4 o;
#pragma unroll
      for (int r = 0; r < 4; ++r) o[r] = (short)f2bf(accO[s][d0][r] * inv);
      *(s16x4*)(ctx + (rowbase + qrow) * D + h * 64 + d0 * 16 + g4) = o;
    }
  }
}

// ---------------------------------------------------------------- launch
extern "C" void kernel_launch(void* const* d_in, const int* in_sizes, int n_in,
                              void* d_out, int out_size, void* d_ws, size_t ws_size,
                              hipStream_t stream) {
  const float* q  = (const float*)d_in[0];
  const float* k  = (const float*)d_in[1];
  const float* v  = (const float*)d_in[2];
  const void*  am = d_in[3];
  const float* hm = (const float*)d_in[4];
  const float* Wq = (const float*)d_in[5];
  const float* bq = (const float*)d_in[6];
  const float* Wk = (const float*)d_in[7];
  const float* bk = (const float*)d_in[8];
  const float* Wv = (const float*)d_in[9];
  const float* bv = (const float*)d_in[10];
  const float* Wo = (const float*)d_in[11];
  const float* bo = (const float*)d_in[12];

  char* ws = (char*)d_ws;
  const size_t MB = 1024 * 1024;
  const bool big = ws_size >= 58 * MB;

  if (big) {
    u16* qb  = (u16*)(ws + 0 * MB);
    u16* kb  = (u16*)(ws + 8 * MB);
    u16* vb  = (u16*)(ws + 16 * MB);
    u16* wqb = (u16*)(ws + 24 * MB);
    u16* wkb = (u16*)(ws + 26 * MB);
    u16* wvb = (u16*)(ws + 28 * MB);
    u16* wob = (u16*)(ws + 30 * MB);
    u16* Qh  = (u16*)(ws + 32 * MB);
    u16* Kh  = (u16*)(ws + 40 * MB);
    u16* Vh  = (u16*)(ws + 48 * MB);
    u64* mbits = (u64*)(ws + 56 * MB);
    u16* ctx = qb;   // qb dead after gemm_qkv

    ConvArgs ca;
    ca.src[0] = q;  ca.dst[0] = qb;  ca.n4[0] = 1048576; ca.scale[0] = 1.f;
    ca.src[1] = k;  ca.dst[1] = kb;  ca.n4[1] = 1048576; ca.scale[1] = 1.f;
    ca.src[2] = v;  ca.dst[2] = vb;  ca.n4[2] = 1048576; ca.scale[2] = 1.f;
    ca.src[3] = Wq; ca.dst[3] = wqb; ca.n4[3] = 262144;  ca.scale[3] = 0.125f * L2E;
    ca.src[4] = Wk; ca.dst[4] = wkb; ca.n4[4] = 262144;  ca.scale[4] = 1.f;
    ca.src[5] = Wv; ca.dst[5] = wvb; ca.n4[5] = 262144;  ca.scale[5] = 1.f;
    ca.src[6] = Wo; ca.dst[6] = wob; ca.n4[6] = 262144;  ca.scale[6] = 1.f;
    convert_many<<<dim3(512, 7), 256, 0, stream>>>(ca);

    mask_to_bits<<<2048, 256, 0, stream>>>((const unsigned int*)am, mbits, 8388608);

    QkvArgsB ga;
    ga.A[0] = qb; ga.B[0] = wqb; ga.bias[0] = bq; ga.bscale[0] = 0.125f * L2E; ga.C[0] = Qh;
    ga.A[1] = kb; ga.B[1] = wkb; ga.bias[1] = bk; ga.bscale[1] = 1.f;          ga.C[1] = Kh;
    ga.A[2] = vb; ga.B[2] = wvb; ga.bias[2] = bv; ga.bscale[2] = 1.f;          ga.C[2] = Vh;
    gemm_qkv_bf<<<dim3(32, 8, 3), 256, 0, stream>>>(ga);

    attn_kernel<<<512, 256, 0, stream>>>(Qh, Kh, Vh, mbits, hm, ctx);

    gemm_out<<<dim3(64, 8), 256, 0, stream>>>(ctx, wob, bo, q, (float*)d_out);
  } else {
    u16* Qh  = (u16*)(ws + 0 * MB);
    u16* Kh  = (u16*)(ws + 8 * MB);
    u16* Vh  = (u16*)(ws + 16 * MB);
    u16* wqb = (u16*)(ws + 24 * MB);
    u16* wkb = (u16*)(ws + 26 * MB);
    u16* wvb = (u16*)(ws + 28 * MB);
    u16* wob = (u16*)(ws + 30 * MB);
    u64* mbits = (u64*)(ws + 32 * MB);
    u16* ctx = (u16*)(ws + 33 * MB);

    ConvArgs ca;
    ca.src[0] = Wq; ca.dst[0] = wqb; ca.n4[0] = 262144; ca.scale[0] = 0.125f * L2E;
    ca.src[1] = Wk; ca.dst[1] = wkb; ca.n4[1] = 262144; ca.scale[1] = 1.f;
    ca.src[2] = Wv; ca.dst[2] = wvb; ca.n4[2] = 262144; ca.scale[2] = 1.f;
    ca.src[3] = Wo; ca.dst[3] = wob; ca.n4[3] = 262144; ca.scale[3] = 1.f;
    convert_many<<<dim3(256, 4), 256, 0, stream>>>(ca);

    mask_to_bits<<<2048, 256, 0, stream>>>((const unsigned int*)am, mbits, 8388608);

    QkvArgsF ga;
    ga.A[0] = q; ga.B[0] = wqb; ga.bias[0] = bq; ga.bscale[0] = 0.125f * L2E; ga.C[0] = Qh;
    ga.A[1] = k; ga.B[1] = wkb; ga.bias[1] = bk; ga.bscale[1] = 1.f;          ga.C[1] = Kh;
    ga.A[2] = v; ga.B[2] = wvb; ga.bias[2] = bv; ga.bscale[2] = 1.f;          ga.C[2] = Vh;
    gemm_qkv_f32<<<dim3(32, 8, 3), 256, 0, stream>>>(ga);

    attn_kernel<<<512, 256, 0, stream>>>(Qh, Kh, Vh, mbits, hm, ctx);

    gemm_out<<<dim3(64, 8), 256, 0, stream>>>(ctx, wob, bo, q, (float*)d_out);
  }
}

// Round 18
// 145.033 us; speedup vs baseline: 1.2383x; 1.0105x over previous
//
#include <hip/hip_runtime.h>

typedef unsigned short u16;
typedef unsigned long long u64;
typedef __attribute__((ext_vector_type(4))) float f32x4;
typedef __attribute__((ext_vector_type(8))) short s16x8;
typedef __attribute__((ext_vector_type(4))) short s16x4;
typedef __attribute__((ext_vector_type(4))) unsigned int u32x4;

#define LDS_LOAD16(gp, lp) __builtin_amdgcn_global_load_lds( \
    (__attribute__((address_space(1))) void*)(gp), \
    (__attribute__((address_space(3))) void*)(lp), 16, 0, 0)

#define MFMA16 __builtin_amdgcn_mfma_f32_16x16x32_bf16

constexpr float L2E = 1.44269504088896340736f;

__device__ __forceinline__ u16 f2bf(float x) {
  unsigned u = __float_as_uint(x);
  u += 0x7FFF + ((u >> 16) & 1);   // RNE
  return (u16)(u >> 16);
}

__device__ __forceinline__ unsigned cvtpk_bf16(float lo, float hi) {
  unsigned r;
  asm("v_cvt_pk_bf16_f32 %0, %1, %2" : "=v"(r) : "v"(lo), "v"(hi));
  return r;
}

// ---------------------------------------------------------------- convert
struct ConvArgs {
  const float* src[7];
  u16* dst[7];
  int n4[7];
  float scale[7];
};

__global__ __launch_bounds__(256) void convert_many(ConvArgs a) {
  const int arr = blockIdx.y;
  const f32x4* src = (const f32x4*)a.src[arr];
  u16* dst = a.dst[arr];
  const int n4 = a.n4[arr];
  const float sc = a.scale[arr];
  const int stride = gridDim.x * blockDim.x;
  for (int i = blockIdx.x * blockDim.x + threadIdx.x; i < n4; i += stride) {
    f32x4 v = src[i];
    s16x4 o;
#pragma unroll
    for (int j = 0; j < 4; ++j) o[j] = (short)f2bf(v[j] * sc);
    *(s16x4*)(dst + (size_t)i * 4) = o;
  }
}

// ---------------------------------------------------------------- mask -> bits
__global__ __launch_bounds__(256) void mask_to_bits(const unsigned int* __restrict__ m32,
                                                    u64* __restrict__ bits,
                                                    int n) {
  const int lane = threadIdx.x & 63;
  unsigned probe = m32[lane];
  bool bytemode = __any(probe > 1u);
  const int stride = gridDim.x * blockDim.x;
  for (int i = blockIdx.x * blockDim.x + threadIdx.x; i < n; i += stride) {
    bool v;
    if (bytemode) v = ((const unsigned char*)m32)[i] != 0;
    else          v = m32[i] != 0;
    u64 b = __ballot(v);
    if (lane == 0) bits[i >> 6] = b;
  }
}

// ---------------------------------------------------------------- QKV GEMM (bf16, T4 pipeline)
struct QkvArgsB {
  const u16* A[3];
  const u16* B[3];
  const float* bias[3];
  float bscale[3];
  u16* C[3];
};

__global__ __launch_bounds__(256) void gemm_qkv_bf(QkvArgsB a) {
  const int z = blockIdx.z;
  const u16* __restrict__ A = a.A[z];
  const u16* __restrict__ B = a.B[z];
  const float* __restrict__ bias = a.bias[z];
  const float bscale = a.bscale[z];
  u16* __restrict__ C = a.C[z];

  __shared__ u16 As[3][4096];
  __shared__ u16 Bs[3][4096];
  const int tid = threadIdx.x;
  const int lane = tid & 63;
  const int wave = tid >> 6;
  const int g = lane >> 4, c = lane & 15;
  const int g4 = g * 4;
  const int bx = blockIdx.x;
  const int row0 = (((bx & 7) << 2) | (bx >> 3)) * 128;   // XCD-chunked rows
  const int col0 = blockIdx.y * 128;
  const int wr = (wave >> 1) * 64, wc = (wave & 1) * 64;

  f32x4 acc[4][4] = {};

#define STAGE_QKV(p_, k0_) { _Pragma("unroll") \
    for (int i = 0; i < 2; ++i) { \
      int e = (i * 256 + tid) * 8; \
      LDS_LOAD16(A + (size_t)(row0 + (e >> 5)) * 1024 + (k0_) + (e & 31), As[p_] + e); \
      LDS_LOAD16(B + (size_t)(col0 + (e >> 5)) * 1024 + (k0_) + (e & 31), Bs[p_] + e); } }

  STAGE_QKV(0, 0);
  STAGE_QKV(1, 32);

  for (int s = 0; s < 32; ++s) {
    const int p = s % 3;
    if (s == 31) asm volatile("s_waitcnt vmcnt(0)" ::: "memory");
    else         asm volatile("s_waitcnt vmcnt(4)" ::: "memory");
    __builtin_amdgcn_s_barrier();
    __builtin_amdgcn_sched_barrier(0);
    if (s + 2 < 32) {
      const int np = (s + 2) % 3;
      STAGE_QKV(np, (s + 2) * 32);
    }
    s16x8 af[4], bf[4];
#pragma unroll
    for (int m = 0; m < 4; ++m) af[m] = *(const s16x8*)(As[p] + (wr + m * 16 + c) * 32 + g * 8);
#pragma unroll
    for (int n = 0; n < 4; ++n) bf[n] = *(const s16x8*)(Bs[p] + (wc + n * 16 + c) * 32 + g * 8);
#pragma unroll
    for (int m = 0; m < 4; ++m)
#pragma unroll
      for (int n = 0; n < 4; ++n)
        acc[m][n] = MFMA16(bf[n], af[m], acc[m][n], 0, 0, 0);   // swapped
  }

  f32x4 bv[4];
#pragma unroll
  for (int n = 0; n < 4; ++n) {
    bv[n] = *(const f32x4*)(bias + col0 + wc + n * 16 + g4);
#pragma unroll
    for (int r = 0; r < 4; ++r) bv[n][r] *= bscale;
  }
#pragma unroll
  for (int m = 0; m < 4; ++m)
#pragma unroll
    for (int n = 0; n < 4; ++n) {
      s16x4 o;
#pragma unroll
      for (int r = 0; r < 4; ++r) o[r] = (short)f2bf(acc[m][n][r] + bv[n][r]);
      *(s16x4*)(C + (size_t)(row0 + wr + m * 16 + c) * 1024 + col0 + wc + n * 16 + g4) = o;
    }
}

// ---------------------------------------------------------------- QKV GEMM (fp32 A, fallback)
struct QkvArgsF {
  const float* A[3];
  const u16* B[3];
  const float* bias[3];
  float bscale[3];
  u16* C[3];
};

__global__ __launch_bounds__(256) void gemm_qkv_f32(QkvArgsF a) {
  const int z = blockIdx.z;
  const float* __restrict__ A = a.A[z];
  const u16* __restrict__ B = a.B[z];
  const float* __restrict__ bias = a.bias[z];
  const float bscale = a.bscale[z];
  u16* __restrict__ C = a.C[z];

  __shared__ u16 As[2][4096];
  __shared__ u16 Bs[2][4096];
  const int tid = threadIdx.x;
  const int lane = tid & 63;
  const int wave = tid >> 6;
  const int g = lane >> 4, c = lane & 15;
  const int g4 = g * 4;
  const int row0 = blockIdx.x * 128;
  const int col0 = blockIdx.y * 128;
  const int wr = (wave >> 1) * 64, wc = (wave & 1) * 64;
  const int ra = tid >> 2;
  const int cca = (tid & 3) * 8;

  f32x4 acc[4][4] = {};
  f32x4 ar[2][2];
#pragma unroll
  for (int i = 0; i < 2; ++i) {
    ar[i][0] = *(const f32x4*)(A + (size_t)(row0 + i * 64 + ra) * 1024 + cca);
    ar[i][1] = *(const f32x4*)(A + (size_t)(row0 + i * 64 + ra) * 1024 + cca + 4);
  }

  for (int s = 0; s < 32; ++s) {
    const int p = s & 1;
    const int k0 = s * 32;
#pragma unroll
    for (int i = 0; i < 2; ++i) {
      unsigned w0 = cvtpk_bf16(ar[i][0][0], ar[i][0][1]);
      unsigned w1 = cvtpk_bf16(ar[i][0][2], ar[i][0][3]);
      unsigned w2 = cvtpk_bf16(ar[i][1][0], ar[i][1][1]);
      unsigned w3 = cvtpk_bf16(ar[i][1][2], ar[i][1][3]);
      union { u32x4 u; s16x8 v; } w;
      w.u = (u32x4){w0, w1, w2, w3};
      *(s16x8*)(As[p] + (i * 256 + tid) * 8) = w.v;
    }
    if (s < 31) {
#pragma unroll
      for (int i = 0; i < 2; ++i) {
        ar[i][0] = *(const f32x4*)(A + (size_t)(row0 + i * 64 + ra) * 1024 + k0 + 32 + cca);
        ar[i][1] = *(const f32x4*)(A + (size_t)(row0 + i * 64 + ra) * 1024 + k0 + 32 + cca + 4);
      }
    }
#pragma unroll
    for (int i = 0; i < 2; ++i) {
      int e = (i * 256 + tid) * 8;
      LDS_LOAD16(B + (size_t)(col0 + (e >> 5)) * 1024 + k0 + (e & 31), Bs[p] + e);
    }
    __syncthreads();

    s16x8 af[4], bf[4];
#pragma unroll
    for (int m = 0; m < 4; ++m) af[m] = *(const s16x8*)(As[p] + (wr + m * 16 + c) * 32 + g * 8);
#pragma unroll
    for (int n = 0; n < 4; ++n) bf[n] = *(const s16x8*)(Bs[p] + (wc + n * 16 + c) * 32 + g * 8);
#pragma unroll
    for (int m = 0; m < 4; ++m)
#pragma unroll
      for (int n = 0; n < 4; ++n)
        acc[m][n] = MFMA16(bf[n], af[m], acc[m][n], 0, 0, 0);
  }

  f32x4 bv[4];
#pragma unroll
  for (int n = 0; n < 4; ++n) {
    bv[n] = *(const f32x4*)(bias + col0 + wc + n * 16 + g4);
#pragma unroll
    for (int r = 0; r < 4; ++r) bv[n][r] *= bscale;
  }
#pragma unroll
  for (int m = 0; m < 4; ++m)
#pragma unroll
    for (int n = 0; n < 4; ++n) {
      s16x4 o;
#pragma unroll
      for (int r = 0; r < 4; ++r) o[r] = (short)f2bf(acc[m][n][r] + bv[n][r]);
      *(s16x4*)(C + (size_t)(row0 + wr + m * 16 + c) * 1024 + col0 + wc + n * 16 + g4) = o;
    }
}

// ---------------------------------------------------------------- out GEMM (T4 pipeline)
__global__ __launch_bounds__(256) void gemm_out(const u16* __restrict__ A,
                                                const u16* __restrict__ B,
                                                const float* __restrict__ bias,
                                                const float* __restrict__ resid,
                                                float* __restrict__ C) {
  __shared__ u16 As[3][2048];
  __shared__ u16 Bs[3][4096];
  const int tid = threadIdx.x;
  const int lane = tid & 63;
  const int wave = tid >> 6;
  const int g = lane >> 4, c = lane & 15;
  const int g4 = g * 4;
  const int bx = blockIdx.x;
  const int row0 = (((bx & 7) << 3) | (bx >> 3)) * 64;    // XCD-chunked rows
  const int col0 = blockIdx.y * 128;
  const int wr = (wave >> 1) * 32, wc = (wave & 1) * 64;

  f32x4 acc[2][4] = {};

#define STAGE_OUT(p_, k0_) { \
    LDS_LOAD16(A + (size_t)(row0 + (tid >> 2)) * 1024 + (k0_) + (tid & 3) * 8, As[p_] + tid * 8); \
    _Pragma("unroll") \
    for (int i = 0; i < 2; ++i) { \
      int e = (i * 256 + tid) * 8; \
      LDS_LOAD16(B + (size_t)(col0 + (e >> 5)) * 1024 + (k0_) + (e & 31), Bs[p_] + e); } }

  STAGE_OUT(0, 0);
  STAGE_OUT(1, 32);

  for (int s = 0; s < 32; ++s) {
    const int p = s % 3;
    if (s == 31) asm volatile("s_waitcnt vmcnt(0)" ::: "memory");
    else         asm volatile("s_waitcnt vmcnt(3)" ::: "memory");
    __builtin_amdgcn_s_barrier();
    __builtin_amdgcn_sched_barrier(0);
    if (s + 2 < 32) {
      const int np = (s + 2) % 3;
      STAGE_OUT(np, (s + 2) * 32);
    }
    s16x8 af[2], bf[4];
#pragma unroll
    for (int m = 0; m < 2; ++m) af[m] = *(const s16x8*)(As[p] + (wr + m * 16 + c) * 32 + g * 8);
#pragma unroll
    for (int n = 0; n < 4; ++n) bf[n] = *(const s16x8*)(Bs[p] + (wc + n * 16 + c) * 32 + g * 8);
#pragma unroll
    for (int m = 0; m < 2; ++m)
#pragma unroll
      for (int n = 0; n < 4; ++n)
        acc[m][n] = MFMA16(bf[n], af[m], acc[m][n], 0, 0, 0);
  }

  f32x4 bv[4];
#pragma unroll
  for (int n = 0; n < 4; ++n) bv[n] = *(const f32x4*)(bias + col0 + wc + n * 16 + g4);
#pragma unroll
  for (int m = 0; m < 2; ++m)
#pragma unroll
    for (int n = 0; n < 4; ++n) {
      size_t off = (size_t)(row0 + wr + m * 16 + c) * 1024 + col0 + wc + n * 16 + g4;
      f32x4 rv = *(const f32x4*)(resid + off);
      f32x4 o;
#pragma unroll
      for (int r = 0; r < 4; ++r) o[r] = acc[m][n][r] + bv[n][r] + rv[r];
      *(f32x4*)(C + off) = o;
    }
}

// ---------------------------------------------------------------- attention
// R17 (counted lgkm-only barrier) + mask-word prefetch one iteration ahead:
// the per-lane mrow[it] global loads were issued right before use, exposing
// ~200cy L2 latency on the QK^T->softmax critical path each iteration.
constexpr float NEGV = -10000000.0f;

__global__ __launch_bounds__(256) void attn_kernel(const u16* __restrict__ Qh,
                                                   const u16* __restrict__ Kh,
                                                   const u16* __restrict__ Vh,
                                                   const u64* __restrict__ mbits,
                                                   const float* __restrict__ head_mask,
                                                   u16* __restrict__ ctx) {
  __shared__ u16 Ks[2][4096];      // d-chunked: [chunk(d/8)][key(64)][d%8]
  __shared__ u16 Vt[2][64 * 72];   // [d][sigma(key) ^ 8*(d>>3)], stride 72

  const int tid = threadIdx.x;
  const int lane = tid & 63;
  const int wave = tid >> 6;
  const int g = lane >> 4, c = lane & 15;
  const int g4 = g * 4;
  const int wid = (blockIdx.x & 7) * 64 + (blockIdx.x >> 3);
  const int qt = wid & 15;
  const int bh = wid >> 4;
  const int b = bh >> 4;
  const int h = bh & 15;
  const size_t rowbase = (size_t)b * 2048;
  const int D = 1024;

  s16x8 qf[2][2];
#pragma unroll
  for (int s = 0; s < 2; ++s) {
    const int qrow = qt * 128 + s * 64 + wave * 16 + c;
#pragma unroll
    for (int ks = 0; ks < 2; ++ks)
      qf[s][ks] = *(const s16x8*)(Qh + (rowbase + qrow) * D + h * 64 + ks * 32 + g * 8);
  }

  f32x4 accO[2][4] = {};
  f32x4 accSum[2] = {};            // ones-MFMA denominator; col q=c

  union { u32x4 u; s16x8 v; } onesu;
  onesu.u = (u32x4){0x3F803F80u, 0x3F803F80u, 0x3F803F80u, 0x3F803F80u};
  const s16x8 onesA = onesu.v;

  const u64* mrow0 = mbits + (rowbase + qt * 128 + 0 * 64 + wave * 16 + c) * 32;
  const u64* mrow1 = mbits + (rowbase + qt * 128 + 1 * 64 + wave * 16 + c) * 32;

  const int kkK = tid & 63;
  const int aV = tid >> 3;
  const int sV = tid & 7;
  const int dcV = sV * 8;
  // sigma(k): k=32K+16H+4G+J -> slot 32K+8G+4H+J  (pairs k=2a,2a+1 stay adjacent)
  const int k2 = 2 * aV;
  const int slotV = (k2 & 32) | (((k2 >> 2) & 3) << 3) | (((k2 >> 4) & 1) << 2) | (k2 & 3);
  const int colV = slotV ^ (8 * sV);

  const u16* Kbase = Kh + rowbase * D + h * 64;
  const u16* Vbase = Vh + rowbase * D + h * 64;

  s16x8 kreg[2], vreg[2];
#define LOADKV(kb_) { \
    kreg[0] = *(const s16x8*)(Kbase + (size_t)((kb_) + kkK) * D + wave * 8); \
    kreg[1] = *(const s16x8*)(Kbase + (size_t)((kb_) + kkK) * D + (4 + wave) * 8); \
    vreg[0] = *(const s16x8*)(Vbase + (size_t)((kb_) + k2) * D + dcV); \
    vreg[1] = *(const s16x8*)(Vbase + (size_t)((kb_) + k2 + 1) * D + dcV); }
#define WRITEKV(p_) { \
    *(s16x8*)(Ks[p_] + tid * 8) = kreg[0]; \
    *(s16x8*)(Ks[p_] + 2048 + tid * 8) = kreg[1]; \
    const unsigned* v0w = (const unsigned*)&vreg[0]; \
    const unsigned* v1w = (const unsigned*)&vreg[1]; \
    _Pragma("unroll") \
    for (int j = 0; j < 8; ++j) { \
      unsigned pk = __builtin_amdgcn_perm(v1w[j >> 1], v0w[j >> 1], \
                                          (j & 1) ? 0x07060302u : 0x05040100u); \
      *(unsigned*)(Vt[p_] + (dcV + j) * 72 + colV) = pk; } }

  LOADKV(0);
  WRITEKV(0);
  LOADKV(64);
  __syncthreads();

  u64 mw0 = mrow0[0], mw1 = mrow1[0];   // prefetched mask words for it=0

#define ATTN_ITER(p_, it_) { \
    const int it = (it_); \
    if (it < 31) WRITEKV(p_ ^ 1); \
    if (it < 30) LOADKV((it + 2) * 64); \
    u64 nmw0 = 0, nmw1 = 0; \
    if (it < 31) { nmw0 = mrow0[it + 1]; nmw1 = mrow1[it + 1]; } \
    f32x4 accS[2][4]; \
    _Pragma("unroll") \
    for (int t = 0; t < 4; ++t) { \
      s16x8 kf0 = *(const s16x8*)(Ks[p_] + ((0 + g) * 64 + t * 16 + c) * 8); \
      s16x8 kf1 = *(const s16x8*)(Ks[p_] + ((4 + g) * 64 + t * 16 + c) * 8); \
      f32x4 z0 = {0.f, 0.f, 0.f, 0.f}; \
      z0 = MFMA16(kf0, qf[0][0], z0, 0, 0, 0); \
      accS[0][t] = MFMA16(kf1, qf[0][1], z0, 0, 0, 0); \
      f32x4 z1 = {0.f, 0.f, 0.f, 0.f}; \
      z1 = MFMA16(kf0, qf[1][0], z1, 0, 0, 0); \
      accS[1][t] = MFMA16(kf1, qf[1][1], z1, 0, 0, 0); \
    } \
    s16x8 vbr[4][2]; \
    _Pragma("unroll") \
    for (int d0 = 0; d0 < 4; ++d0) { \
      const int dd = d0 * 16 + c; \
      const int sw8 = (d0 * 2 + (c >> 3)) * 8; \
      _Pragma("unroll") \
      for (int ks = 0; ks < 2; ++ks) \
        vbr[d0][ks] = *(const s16x8*)(Vt[p_] + dd * 72 + ((ks * 32 + g * 8) ^ sw8)); \
    } \
    s16x8 pa[2][2]; \
    _Pragma("unroll") \
    for (int s = 0; s < 2; ++s) { \
      u64 mw = (s == 0) ? mw0 : mw1; \
      u64 sh = mw >> g4; \
      unsigned mlo = (unsigned)sh, mhi = (unsigned)(sh >> 32); \
      unsigned pk0[4], pk1[4]; \
      _Pragma("unroll") \
      for (int t = 0; t < 4; ++t) { \
        unsigned msrc = (t < 2) ? mlo : mhi; \
        _Pragma("unroll") \
        for (int r = 0; r < 4; ++r) { \
          float sv = accS[s][t][r]; \
          if ((msrc >> ((t & 1) * 16 + r)) & 1) sv = NEGV; \
          float pv; \
          asm("v_exp_f32 %0, %1" : "=v"(pv) : "v"(sv)); \
          accS[s][t][r] = pv; \
        } \
        pk0[t] = cvtpk_bf16(accS[s][t][0], accS[s][t][1]); \
        pk1[t] = cvtpk_bf16(accS[s][t][2], accS[s][t][3]); \
      } \
      _Pragma("unroll") \
      for (int ks = 0; ks < 2; ++ks) { \
        union { u32x4 u; s16x8 v; } w; \
        w.u = (u32x4){pk0[2 * ks], pk1[2 * ks], pk0[2 * ks + 1], pk1[2 * ks + 1]}; \
        pa[s][ks] = w.v; \
      } \
    } \
    _Pragma("unroll") \
    for (int d0 = 0; d0 < 4; ++d0) \
      _Pragma("unroll") \
      for (int ks = 0; ks < 2; ++ks) { \
        accO[0][d0] = MFMA16(vbr[d0][ks], pa[0][ks], accO[0][d0], 0, 0, 0); \
        accO[1][d0] = MFMA16(vbr[d0][ks], pa[1][ks], accO[1][d0], 0, 0, 0); \
      } \
    _Pragma("unroll") \
    for (int ks = 0; ks < 2; ++ks) { \
      accSum[0] = MFMA16(onesA, pa[0][ks], accSum[0], 0, 0, 0); \
      accSum[1] = MFMA16(onesA, pa[1][ks], accSum[1], 0, 0, 0); \
    } \
    mw0 = nmw0; mw1 = nmw1; \
    asm volatile("s_waitcnt lgkmcnt(0)" ::: "memory"); \
    __builtin_amdgcn_s_barrier(); \
    __builtin_amdgcn_sched_barrier(0); }

  for (int it2 = 0; it2 < 16; ++it2) {
    ATTN_ITER(0, 2 * it2);
    ATTN_ITER(1, 2 * it2 + 1);
  }

  const float hm = head_mask[0];
#pragma unroll
  for (int s = 0; s < 2; ++s) {
    float inv = hm / accSum[s][0];
    const int qrow = qt * 128 + s * 64 + wave * 16 + c;
#pragma unroll
    for (int d0 = 0; d0 < 4; ++d0) {
      s16x4 o;
#pragma unroll
      for (int r = 0; r < 4; ++r) o[r] = (short)f2bf(accO[s][d0][r] * inv);
      *(s16x4*)(ctx + (rowbase + qrow) * D + h * 64 + d0 * 16 + g4) = o;
    }
  }
}

// ---------------------------------------------------------------- launch
extern "C" void kernel_launch(void* const* d_in, const int* in_sizes, int n_in,
                              void* d_out, int out_size, void* d_ws, size_t ws_size,
                              hipStream_t stream) {
  const float* q  = (const float*)d_in[0];
  const float* k  = (const float*)d_in[1];
  const float* v  = (const float*)d_in[2];
  const void*  am = d_in[3];
  const float* hm = (const float*)d_in[4];
  const float* Wq = (const float*)d_in[5];
  const float* bq = (const float*)d_in[6];
  const float* Wk = (const float*)d_in[7];
  const float* bk = (const float*)d_in[8];
  const float* Wv = (const float*)d_in[9];
  const float* bv = (const float*)d_in[10];
  const float* Wo = (const float*)d_in[11];
  const float* bo = (const float*)d_in[12];

  char* ws = (char*)d_ws;
  const size_t MB = 1024 * 1024;
  const bool big = ws_size >= 58 * MB;

  if (big) {
    u16* qb  = (u16*)(ws + 0 * MB);
    u16* kb  = (u16*)(ws + 8 * MB);
    u16* vb  = (u16*)(ws + 16 * MB);
    u16* wqb = (u16*)(ws + 24 * MB);
    u16* wkb = (u16*)(ws + 26 * MB);
    u16* wvb = (u16*)(ws + 28 * MB);
    u16* wob = (u16*)(ws + 30 * MB);
    u16* Qh  = (u16*)(ws + 32 * MB);
    u16* Kh  = (u16*)(ws + 40 * MB);
    u16* Vh  = (u16*)(ws + 48 * MB);
    u64* mbits = (u64*)(ws + 56 * MB);
    u16* ctx = qb;   // qb dead after gemm_qkv

    ConvArgs ca;
    ca.src[0] = q;  ca.dst[0] = qb;  ca.n4[0] = 1048576; ca.scale[0] = 1.f;
    ca.src[1] = k;  ca.dst[1] = kb;  ca.n4[1] = 1048576; ca.scale[1] = 1.f;
    ca.src[2] = v;  ca.dst[2] = vb;  ca.n4[2] = 1048576; ca.scale[2] = 1.f;
    ca.src[3] = Wq; ca.dst[3] = wqb; ca.n4[3] = 262144;  ca.scale[3] = 0.125f * L2E;
    ca.src[4] = Wk; ca.dst[4] = wkb; ca.n4[4] = 262144;  ca.scale[4] = 1.f;
    ca.src[5] = Wv; ca.dst[5] = wvb; ca.n4[5] = 262144;  ca.scale[5] = 1.f;
    ca.src[6] = Wo; ca.dst[6] = wob; ca.n4[6] = 262144;  ca.scale[6] = 1.f;
    convert_many<<<dim3(512, 7), 256, 0, stream>>>(ca);

    mask_to_bits<<<2048, 256, 0, stream>>>((const unsigned int*)am, mbits, 8388608);

    QkvArgsB ga;
    ga.A[0] = qb; ga.B[0] = wqb; ga.bias[0] = bq; ga.bscale[0] = 0.125f * L2E; ga.C[0] = Qh;
    ga.A[1] = kb; ga.B[1] = wkb; ga.bias[1] = bk; ga.bscale[1] = 1.f;          ga.C[1] = Kh;
    ga.A[2] = vb; ga.B[2] = wvb; ga.bias[2] = bv; ga.bscale[2] = 1.f;          ga.C[2] = Vh;
    gemm_qkv_bf<<<dim3(32, 8, 3), 256, 0, stream>>>(ga);

    attn_kernel<<<512, 256, 0, stream>>>(Qh, Kh, Vh, mbits, hm, ctx);

    gemm_out<<<dim3(64, 8), 256, 0, stream>>>(ctx, wob, bo, q, (float*)d_out);
  } else {
    u16* Qh  = (u16*)(ws + 0 * MB);
    u16* Kh  = (u16*)(ws + 8 * MB);
    u16* Vh  = (u16*)(ws + 16 * MB);
    u16* wqb = (u16*)(ws + 24 * MB);
    u16* wkb = (u16*)(ws + 26 * MB);
    u16* wvb = (u16*)(ws + 28 * MB);
    u16* wob = (u16*)(ws + 30 * MB);
    u64* mbits = (u64*)(ws + 32 * MB);
    u16* ctx = (u16*)(ws + 33 * MB);

    ConvArgs ca;
    ca.src[0] = Wq; ca.dst[0] = wqb; ca.n4[0] = 262144; ca.scale[0] = 0.125f * L2E;
    ca.src[1] = Wk; ca.dst[1] = wkb; ca.n4[1] = 262144; ca.scale[1] = 1.f;
    ca.src[2] = Wv; ca.dst[2] = wvb; ca.n4[2] = 262144; ca.scale[2] = 1.f;
    ca.src[3] = Wo; ca.dst[3] = wob; ca.n4[3] = 262144; ca.scale[3] = 1.f;
    convert_many<<<dim3(256, 4), 256, 0, stream>>>(ca);

    mask_to_bits<<<2048, 256, 0, stream>>>((const unsigned int*)am, mbits, 8388608);

    QkvArgsF ga;
    ga.A[0] = q; ga.B[0] = wqb; ga.bias[0] = bq; ga.bscale[0] = 0.125f * L2E; ga.C[0] = Qh;
    ga.A[1] = k; ga.B[1] = wkb; ga.bias[1] = bk; ga.bscale[1] = 1.f;          ga.C[1] = Kh;
    ga.A[2] = v; ga.B[2] = wvb; ga.bias[2] = bv; ga.bscale[2] = 1.f;          ga.C[2] = Vh;
    gemm_qkv_f32<<<dim3(32, 8, 3), 256, 0, stream>>>(ga);

    attn_kernel<<<512, 256, 0, stream>>>(Qh, Kh, Vh, mbits, hm, ctx);

    gemm_out<<<dim3(64, 8), 256, 0, stream>>>(ctx, wob, bo, q, (float*)d_out);
  }
}